// Round 5
// baseline (1680.654 us; speedup 1.0000x reference)
//
#include <hip/hip_runtime.h>
#include <hip/hip_fp16.h>
#include <math.h>

#define IN_DIM 128
#define HD 256
#define EPSLN 1e-5f

typedef _Float16 half8 __attribute__((ext_vector_type(8)));
typedef float f32x4 __attribute__((ext_vector_type(4)));
typedef float f32x2 __attribute__((ext_vector_type(2)));

// ---------------- helpers ----------------
__device__ inline void store4(float* p, float4 o) { *(float4*)p = o; }
__device__ inline void store4(__half* p, float4 o) {
    union { uint2 u; __half2 h[2]; } s;
    s.h[0] = __floats2half2_rn(o.x, o.y);
    s.h[1] = __floats2half2_rn(o.z, o.w);
    *(uint2*)p = s.u;
}
__device__ inline float4 h4_to_f4(uint2 u) {
    union { unsigned int w; __half2 h; } a, b;
    a.w = u.x; b.w = u.y;
    float2 lo = __half22float2(a.h), hi = __half22float2(b.h);
    return make_float4(lo.x, lo.y, hi.x, hi.y);
}
// 4 floats -> 4 packed fp8 e4m3 (OCP, gfx950 HW cvt)
__device__ inline unsigned int f4_to_fp8x4(float a, float b, float c, float d) {
    int v = 0;
    v = __builtin_amdgcn_cvt_pk_fp8_f32(a, b, v, false);
    v = __builtin_amdgcn_cvt_pk_fp8_f32(c, d, v, true);
    return (unsigned int)v;
}
__device__ inline float4 fp8x4_to_f4(unsigned int u) {
    f32x2 lo = __builtin_amdgcn_cvt_pk_f32_fp8((int)u, false);
    f32x2 hi = __builtin_amdgcn_cvt_pk_f32_fp8((int)u, true);
    return make_float4(lo.x, lo.y, hi.x, hi.y);
}

__device__ inline void async_copy16(const __half* g, _Float16* l) {
    __builtin_amdgcn_global_load_lds(
        (const __attribute__((address_space(1))) void*)g,
        (__attribute__((address_space(3))) void*)l,
        16, 0, 0);
}

// Packed output column mapping: q[0:256) | kv-interleaved[256:768) | skip[768:1024)
__device__ inline void unpermute_col(int n, int& sel, int& c) {
    if (n < 256) { sel = 0; c = n; }
    else if (n < 768) {
        int j = n - 256, chunk = j >> 3, w = j & 7;
        if (w < 4) { sel = 1; c = chunk * 4 + w; }
        else       { sel = 2; c = chunk * 4 + w - 4; }
    } else { sel = 3; c = n - 768; }
}

// ---------------- fused prep: pack x, pack weights/biases, count degrees + ranks ----
__global__ void prep_k(
    const float4* __restrict__ x, __half* __restrict__ xh, int total4,
    const int* __restrict__ dst, int* __restrict__ counts, int* __restrict__ rank, int E,
    const float* __restrict__ Wq1, const float* __restrict__ Wk1,
    const float* __restrict__ Wv1, const float* __restrict__ Ws1,
    const float* __restrict__ Wq2, const float* __restrict__ Wk2,
    const float* __restrict__ Wv2, const float* __restrict__ Ws2,
    const float* __restrict__ Wo,
    const float* __restrict__ bq1, const float* __restrict__ bk1,
    const float* __restrict__ bv1, const float* __restrict__ bs1,
    const float* __restrict__ bq2, const float* __restrict__ bk2,
    const float* __restrict__ bv2, const float* __restrict__ bs2,
    __half* __restrict__ Wc1, __half* __restrict__ Wc2, __half* __restrict__ Wot,
    float* __restrict__ bc1, float* __restrict__ bc2)
{
    int idx = blockIdx.x * 256 + threadIdx.x;
    if (idx < total4) store4(xh + (size_t)idx * 4, x[idx]);
    if (idx < E) rank[idx] = atomicAdd(&counts[dst[idx]], 1);   // rank within dst bucket
    if (idx < 131072) {
        int n = idx >> 7, k = idx & 127;
        int sel, c; unpermute_col(n, sel, c);
        const float* W = (sel == 0) ? Wq1 : (sel == 1) ? Wk1 : (sel == 2) ? Wv1 : Ws1;
        Wc1[idx] = __float2half(W[(size_t)k * 256 + c]);
    } else if (idx < 393216) {
        int j = idx - 131072;
        int n = j >> 8, k = j & 255;
        int sel, c; unpermute_col(n, sel, c);
        const float* W = (sel == 0) ? Wq2 : (sel == 1) ? Wk2 : (sel == 2) ? Wv2 : Ws2;
        Wc2[j] = __float2half(W[(size_t)k * 256 + c]);
    } else if (idx < 409600) {
        int j = idx - 393216;
        int n = j >> 8, k = j & 255;
        Wot[j] = __float2half(Wo[(size_t)k * 64 + n]);
    } else if (idx < 410624) {
        int n = idx - 409600;
        int sel, c; unpermute_col(n, sel, c);
        const float* b = (sel == 0) ? bq1 : (sel == 1) ? bk1 : (sel == 2) ? bv1 : bs1;
        bc1[n] = b[c];
    } else if (idx < 411648) {
        int n = idx - 410624;
        int sel, c; unpermute_col(n, sel, c);
        const float* b = (sel == 0) ? bq2 : (sel == 1) ? bk2 : (sel == 2) ? bv2 : bs2;
        bc2[n] = b[c];
    }
}

// ---------------- MFMA GEMM: C[M x Nc] = A[M x K] @ Wt^T + bias (f16 out) ----------------
// R13: 1-D grid + XCD-grouping swizzle (measured R4: ~44us win across both gemms).
#define BM 128
#define BN 128
#define BK 64
#define TROWB 272   // f16 out-tile row stride (bytes)

__global__ __launch_bounds__(256) void gemm_mfma(
    const __half* __restrict__ A, const __half* __restrict__ Wt,
    const float* __restrict__ bias, __half* __restrict__ C,
    unsigned char* __restrict__ kv8,
    int M, int K, int Nc)
{
    __shared__ char smem[BM * TROWB];
    _Float16* As = (_Float16*)smem;
    _Float16* Bs = (_Float16*)(smem + 16384);

    int tid = threadIdx.x;
    int lane = tid & 63, w = tid >> 6;
    int wm = w >> 1, wn = w & 1;
    int quad = lane >> 4, l16 = lane & 15;
    // XCD swizzle: nwg = nbx*8 (exact multiple of 8 XCDs)
    int nbx = (int)gridDim.x >> 3;
    int wkr = ((int)blockIdx.x & 7) * nbx + ((int)blockIdx.x >> 3);
    int row0 = (wkr >> 3) * BM;
    int col0 = (wkr & 7) * BN;

    f32x4 acc[4][4];
#pragma unroll
    for (int i = 0; i < 4; i++)
#pragma unroll
        for (int j = 0; j < 4; j++) acc[i][j] = (f32x4){0.f, 0.f, 0.f, 0.f};

    int srow = lane >> 3;
    int schunk = lane & 7;

    for (int k0 = 0; k0 < K; k0 += BK) {
#pragma unroll
        for (int t = 0; t < 4; t++) {
            int r = w * 32 + t * 8 + srow;
            int gr = row0 + r; if (gr > M - 1) gr = M - 1;
            int gchunk = schunk ^ (r & 7);
            async_copy16(&A[(size_t)gr * K + k0 + gchunk * 8], &As[(w * 32 + t * 8) * 64]);
        }
#pragma unroll
        for (int t = 0; t < 4; t++) {
            int r = w * 32 + t * 8 + srow;
            int gc = col0 + r; if (gc > Nc - 1) gc = Nc - 1;
            int gchunk = schunk ^ (r & 7);
            async_copy16(&Wt[(size_t)gc * K + k0 + gchunk * 8], &Bs[(w * 32 + t * 8) * 64]);
        }
        __syncthreads();

#pragma unroll
        for (int ks = 0; ks < 2; ks++) {
            half8 af[4], bf[4];
#pragma unroll
            for (int i = 0; i < 4; i++) {
                int ra = wm * 64 + i * 16 + l16;
                af[i] = *(half8*)&As[ra * 64 + (((ks * 4 + quad) ^ (ra & 7)) * 8)];
                int rb = wn * 64 + i * 16 + l16;
                bf[i] = *(half8*)&Bs[rb * 64 + (((ks * 4 + quad) ^ (rb & 7)) * 8)];
            }
#pragma unroll
            for (int i = 0; i < 4; i++)
#pragma unroll
                for (int j = 0; j < 4; j++)
                    acc[i][j] = __builtin_amdgcn_mfma_f32_16x16x32_f16(af[i], bf[j], acc[i][j], 0, 0, 0);
        }
        __syncthreads();
    }

#pragma unroll
    for (int j = 0; j < 4; j++) {
        int tcol = wn * 64 + j * 16 + l16;
        float bb = (col0 + tcol < Nc) ? bias[col0 + tcol] : 0.f;
#pragma unroll
        for (int i = 0; i < 4; i++) {
#pragma unroll
            for (int r = 0; r < 4; r++) {
                int trow = wm * 64 + i * 16 + quad * 4 + r;
                ((__half*)(smem + trow * TROWB))[tcol] = __float2half(acc[i][j][r] + bb);
            }
        }
    }
    __syncthreads();
    bool iskv = (col0 >= 256) && (col0 < 768);
    int crow = tid >> 4, cchunk = tid & 15;
    for (int p = 0; p < 8; p++) {
        int trow = p * 16 + crow;
        int grow = row0 + trow;
        if (grow >= M) continue;
        uint4 val = *(uint4*)(smem + trow * TROWB + cchunk * 16);
        if (iskv) {
            float4 lo = h4_to_f4(make_uint2(val.x, val.y));
            float4 hi = h4_to_f4(make_uint2(val.z, val.w));
            uint2 o8;
            o8.x = f4_to_fp8x4(lo.x, lo.y, lo.z, lo.w);
            o8.y = f4_to_fp8x4(hi.x, hi.y, hi.z, hi.w);
            *(uint2*)&kv8[(size_t)grow * 512 + (col0 - 256) + cchunk * 8] = o8;
        } else {
            *(uint4*)&C[(size_t)grow * Nc + col0 + cchunk * 8] = val;
        }
    }
}

// ---------------- output GEMM: D[M x 64] = A[M x 256] @ Wot^T + bo (fp32 out) ----------
__global__ __launch_bounds__(256) void gemm_out_k(
    const __half* __restrict__ A, const __half* __restrict__ Wot,
    const float* __restrict__ bias, float* __restrict__ D, int M)
{
    __shared__ _Float16 As[128 * 64];   // 16 KB
    __shared__ _Float16 Bs[64 * 64];    // 8 KB
    int tid = threadIdx.x;
    int lane = tid & 63, w = tid >> 6;
    int quad = lane >> 4, l16 = lane & 15;
    int row0 = blockIdx.x * 128;
    const int K = 256;

    f32x4 acc[2][4];
#pragma unroll
    for (int i = 0; i < 2; i++)
#pragma unroll
        for (int j = 0; j < 4; j++) acc[i][j] = (f32x4){0.f, 0.f, 0.f, 0.f};

    int srow = lane >> 3;
    int schunk = lane & 7;

    for (int k0 = 0; k0 < K; k0 += BK) {
#pragma unroll
        for (int t = 0; t < 4; t++) {
            int r = w * 32 + t * 8 + srow;
            int gr = row0 + r; if (gr > M - 1) gr = M - 1;
            int gchunk = schunk ^ (r & 7);
            async_copy16(&A[(size_t)gr * K + k0 + gchunk * 8], &As[(w * 32 + t * 8) * 64]);
        }
#pragma unroll
        for (int t = 0; t < 2; t++) {
            int r = w * 16 + t * 8 + srow;     // 64 weight rows
            int gchunk = schunk ^ (r & 7);
            async_copy16(&Wot[(size_t)r * K + k0 + gchunk * 8], &Bs[(w * 16 + t * 8) * 64]);
        }
        __syncthreads();

#pragma unroll
        for (int ks = 0; ks < 2; ks++) {
            half8 af[2], bf[4];
#pragma unroll
            for (int i = 0; i < 2; i++) {
                int ra = w * 32 + i * 16 + l16;
                af[i] = *(half8*)&As[ra * 64 + (((ks * 4 + quad) ^ (ra & 7)) * 8)];
            }
#pragma unroll
            for (int j = 0; j < 4; j++) {
                int rb = j * 16 + l16;
                bf[j] = *(half8*)&Bs[rb * 64 + (((ks * 4 + quad) ^ (rb & 7)) * 8)];
            }
#pragma unroll
            for (int i = 0; i < 2; i++)
#pragma unroll
                for (int j = 0; j < 4; j++)
                    acc[i][j] = __builtin_amdgcn_mfma_f32_16x16x32_f16(af[i], bf[j], acc[i][j], 0, 0, 0);
        }
        __syncthreads();
    }

#pragma unroll
    for (int i = 0; i < 2; i++) {
#pragma unroll
        for (int j = 0; j < 4; j++) {
            int gcol = j * 16 + l16;
            float bb = bias[gcol];
#pragma unroll
            for (int r = 0; r < 4; r++) {
                int grow = row0 + w * 32 + i * 16 + quad * 4 + r;
                if (grow < M) D[(size_t)grow * 64 + gcol] = acc[i][j][r] + bb;
            }
        }
    }
}

// ---------------- edge bucketing ----------------
__global__ __launch_bounds__(1024) void scan_k(const int* __restrict__ counts,
                                               int* __restrict__ offs, int n)
{
    __shared__ int wsum[16];
    __shared__ int wpre[16];
    int tid = threadIdx.x, lane = tid & 63, wid = tid >> 6;
    int per = (n + 1023) / 1024;
    int start = tid * per, end = min(start + per, n);
    int sum = 0;
    for (int i = start; i < end; i++) sum += counts[i];
    int v = sum;
#pragma unroll
    for (int d = 1; d < 64; d <<= 1) {
        int t = __shfl_up(v, (unsigned)d, 64);
        if (lane >= d) v += t;
    }
    if (lane == 63) wsum[wid] = v;
    __syncthreads();
    if (tid == 0) {
        int acc = 0;
        for (int i = 0; i < 16; i++) { wpre[i] = acc; acc += wsum[i]; }
    }
    __syncthreads();
    int pre = wpre[wid] + v - sum;
    for (int i = start; i < end; i++) { offs[i] = pre; pre += counts[i]; }
    if (end == n && start <= n) offs[n] = pre;
}

// atomic-free: position = segment offset + precomputed rank
__global__ void scatter_k(const int* __restrict__ src, const int* __restrict__ dst,
                          const float* __restrict__ attr, const int* __restrict__ offs,
                          const int* __restrict__ rank, int2* __restrict__ edat, int E)
{
    int e = blockIdx.x * 256 + threadIdx.x;
    if (e < 8) edat[E + e] = make_int2(0, 0);
    if (e < E) {
        int p = offs[dst[e]] + rank[e];
        edat[p] = make_int2(src[e], __float_as_int(attr[e]));
    }
}

// ---------------- attention: one wave per dst node, batched online softmax ----
// 2048 persistent blocks (proven R8/R10 config; do not shrink block lifetime).
// R12: batch-of-8 deferred-max softmax (one m-merge/corr-exp/rescale per batch).
// R13: within-node ping-pong + SGPR-hoisted edge metadata.
// R14: CROSS-NODE pipeline. avg degree 16 => only 2 batches/node, so the
// per-node serial chain (q -> offs -> edat -> gather) re-serialized every
// node. Now: next node's q+offs prefetch at iteration start (a full node
// ahead), and next node's FIRST gather batch issues into the free ping-pong
// buffer before the current node's last COMPUTE. Pad gathers clamped to
// edge 0 of the batch (L1 dup-hit) to kill the R13 FETCH overshoot.
// We -> LDS so VGPR stays <=64 (occupancy cliff, m69).
__global__ __launch_bounds__(256, 8) void attn_k(
    const uint2* __restrict__ q2, const uint2* __restrict__ kv8u2,
    const float* __restrict__ We,
    __half* __restrict__ hwork, const int2* __restrict__ edat,
    const int* __restrict__ offs,
    double* __restrict__ stats, int n, int nGroups)
{
    __shared__ float4 weLds[64];
    __shared__ float red[8];
    int lane = threadIdx.x & 63;
    int wid = threadIdx.x >> 6;
    if (threadIdx.x < 64) weLds[threadIdx.x] = ((const float4*)We)[threadIdx.x];
    __syncthreads();
    float tsum = 0.f, tsq = 0.f;

    int abA[8], srA[8], abB[8], srB[8];   // SGPR: attr bits / src index
    uint2 kvA[8], kvB[8];

    int g = blockIdx.x;
    // prologue: prefetch first node's q + offs
    uint2 qraw = make_uint2(0u, 0u);
    int i0 = 0, i1 = 0;
    if (g < nGroups) {
        int node = g * 4 + wid;
        if (node < n) {
            qraw = q2[(size_t)node * 256 + lane];
            i0 = __builtin_amdgcn_readfirstlane(offs[node]);
            i1 = __builtin_amdgcn_readfirstlane(offs[node + 1]);
        }
    }
    bool carry = false, carryB = false;

    for (; g < nGroups; g += gridDim.x) {
        int node = g * 4 + wid;
        if (node >= n) continue;           // (n%4==0 in practice; kept for safety)

        // ---- prefetch NEXT node's q + offs (used a full node later) ----
        int gN = g + gridDim.x;
        uint2 qrawN = make_uint2(0u, 0u);
        int i0N = 0, i1N = 0;
        if (gN < nGroups) {
            int nodeN = gN * 4 + wid;
            qrawN = q2[(size_t)nodeN * 256 + lane];
            i0N = __builtin_amdgcn_readfirstlane(offs[nodeN]);
            i1N = __builtin_amdgcn_readfirstlane(offs[nodeN + 1]);
        }
        bool hasNext = (i0N < i1N);

        // ---- current node setup ----
        float4 we = weLds[lane];
        float4 qv = h4_to_f4(qraw);
        float qwe = qv.x * we.x + qv.y * we.y + qv.z * we.z + qv.w * we.w;
        qwe += __shfl_xor(qwe, 1);
        qwe += __shfl_xor(qwe, 2);
        qwe += __shfl_xor(qwe, 4);

        float4 accv = make_float4(0.f, 0.f, 0.f, 0.f);
        float sat = 0.f;
        float m = -INFINITY, l = 0.f;

        auto LOADB = [&](int base, int cnt, int* ab_, int* sr_, uint2* kv_) {
#pragma unroll
            for (int u = 0; u < 8; u++) {
                int2 ed = edat[base + ((u < cnt) ? u : 0)];   // clamp: dup -> L1 hit
                sr_[u] = __builtin_amdgcn_readfirstlane(ed.x);
                ab_[u] = __builtin_amdgcn_readfirstlane(ed.y);
            }
#pragma unroll
            for (int u = 0; u < 8; u++)
                kv_[u] = (kv8u2 + (size_t)(unsigned)sr_[u] * 64)[lane];
        };

        auto COMPUTE = [&](const int* ab_, const uint2* kv_, int cnt) {
            float pv[8];
#pragma unroll
            for (int u = 0; u < 8; u++) {
                float4 kvf = fp8x4_to_f4(kv_[u].x);
                float p = qv.x * kvf.x + qv.y * kvf.y + qv.z * kvf.z + qv.w * kvf.w;
                p += __shfl_xor(p, 1);
                p += __shfl_xor(p, 2);
                p += __shfl_xor(p, 4);
                p = fmaf(__int_as_float(ab_[u]), qwe, p) * 0.17677669529663687f;
                pv[u] = (u < cnt) ? p : -INFINITY;            // folds away for cnt=8
            }
            float m01 = fmaxf(pv[0], pv[1]), m23 = fmaxf(pv[2], pv[3]);
            float m45 = fmaxf(pv[4], pv[5]), m67 = fmaxf(pv[6], pv[7]);
            float pmax = fmaxf(fmaxf(m01, m23), fmaxf(m45, m67));
            float mn = fmaxf(m, pmax);
            float corr = __expf(m - mn);
            l *= corr;
            sat *= corr;
            accv.x *= corr; accv.y *= corr; accv.z *= corr; accv.w *= corr;
#pragma unroll
            for (int u = 0; u < 8; u++) {
                float wgt = __expf(pv[u] - mn);               // pad: exp(-inf)=0
                l += wgt;
                sat = fmaf(wgt, __int_as_float(ab_[u]), sat);
                float4 vv = fp8x4_to_f4(kv_[u].y);
                accv.x = fmaf(wgt, vv.x, accv.x);
                accv.y = fmaf(wgt, vv.y, accv.y);
                accv.z = fmaf(wgt, vv.z, accv.z);
                accv.w = fmaf(wgt, vv.w, accv.w);
            }
            m = mn;
        };

        bool ncarry = false, ncarryB = false;
        if (i0 < i1) {
            int i = i0;
            bool curB;
            if (carry) { curB = carryB; }
            else       { LOADB(i0, min(8, i1 - i0), abA, srA, kvA); curB = false; }
            while (true) {
                int rem = i1 - i;
                if (rem > 8) {
                    int c2 = min(8, rem - 8);
                    if (curB) LOADB(i + 8, c2, abA, srA, kvA);
                    else      LOADB(i + 8, c2, abB, srB, kvB);
                    if (curB) COMPUTE(abB, kvB, 8);
                    else      COMPUTE(abA, kvA, 8);
                    i += 8; curB = !curB;
                } else {
                    if (hasNext) {
                        int c0 = min(8, i1N - i0N);
                        if (curB) LOADB(i0N, c0, abA, srA, kvA);
                        else      LOADB(i0N, c0, abB, srB, kvB);
                        ncarry = true; ncarryB = !curB;
                    }
                    if (curB) COMPUTE(abB, kvB, rem);
                    else      COMPUTE(abA, kvA, rem);
                    break;
                }
            }
        } else {
            // degree-0 node (rare): still prefetch next node's first batch
            if (hasNext) {
                LOADB(i0N, min(8, i1N - i0N), abA, srA, kvA);
                ncarry = true; ncarryB = false;
            }
        }

        // ---- epilogue ----
        float inv = (l > 0.f) ? 1.f / l : 0.f;
        float4 sk = h4_to_f4(q2[(size_t)node * 256 + 192 + lane]);
        float4 we2 = weLds[lane];
        float sw = sat * inv;
        float4 o;
        o.x = fmaf(accv.x, inv, fmaf(sw, we2.x, sk.x));
        o.y = fmaf(accv.y, inv, fmaf(sw, we2.y, sk.y));
        o.z = fmaf(accv.z, inv, fmaf(sw, we2.z, sk.z));
        o.w = fmaf(accv.w, inv, fmaf(sw, we2.w, sk.w));
        store4(hwork + (size_t)node * 256 + lane * 4, o);
        tsum += o.x + o.y + o.z + o.w;
        tsq += o.x * o.x + o.y * o.y + o.z * o.z + o.w * o.w;

        // ---- rotate node state ----
        qraw = qrawN; i0 = i0N; i1 = i1N;
        carry = ncarry; carryB = ncarryB;
    }

#pragma unroll
    for (int d = 1; d < 64; d <<= 1) {
        tsum += __shfl_xor(tsum, d);
        tsq += __shfl_xor(tsq, d);
    }
    if (lane == 0) { red[wid] = tsum; red[4 + wid] = tsq; }
    __syncthreads();
    if (threadIdx.x == 0) {
        double s = (double)red[0] + (double)red[1] + (double)red[2] + (double)red[3];
        double sq = (double)red[4] + (double)red[5] + (double)red[6] + (double)red[7];
        atomicAdd(&stats[0], s);
        atomicAdd(&stats[1], sq);
    }
}

// ---------------- LayerNorm apply (f16 in, f16 out; 4 elems/thread) ----------------
__global__ __launch_bounds__(256) void ln_apply(
    const uint2* __restrict__ in, __half* __restrict__ out,
    const float4* __restrict__ w4, const float4* __restrict__ b4,
    const double* __restrict__ stats, double cnt, int total4)
{
    int base = (blockIdx.x * 256 + threadIdx.x) * 4;
    if (base >= total4) return;
    double mu = stats[0] / cnt;
    double var = stats[1] / cnt - mu * mu;
    if (var < 0.0) var = 0.0;
    float mean = (float)mu;
    float inv = (float)(1.0 / (sqrt(var) + (double)EPSLN));
#pragma unroll
    for (int u = 0; u < 4; u++) {
        int i = base + u;
        if (i >= total4) return;
        int c = i & 63;
        float4 xv = h4_to_f4(in[i]);
        float4 w = w4[c], b = b4[c];
        float4 o;
        o.x = fmaf((xv.x - mean) * inv, w.x, b.x);
        o.y = fmaf((xv.y - mean) * inv, w.y, b.y);
        o.z = fmaf((xv.z - mean) * inv, w.z, b.z);
        o.w = fmaf((xv.w - mean) * inv, w.w, b.w);
        o.x = o.x > 0.f ? o.x : expm1f(o.x);
        o.y = o.y > 0.f ? o.y : expm1f(o.y);
        o.z = o.z > 0.f ? o.z : expm1f(o.z);
        o.w = o.w > 0.f ? o.w : expm1f(o.w);
        store4(out + (size_t)i * 4, o);
    }
}

// ---------------- driver ----------------
extern "C" void kernel_launch(void* const* d_in, const int* in_sizes, int n_in,
                              void* d_out, int out_size, void* d_ws, size_t ws_size,
                              hipStream_t stream)
{
    const float* x      = (const float*)d_in[0];
    const int*   ei     = (const int*)d_in[1];
    const float* eattr  = (const float*)d_in[2];
    const float* Wq1 = (const float*)d_in[3];  const float* bq1 = (const float*)d_in[4];
    const float* Wk1 = (const float*)d_in[5];  const float* bk1 = (const float*)d_in[6];
    const float* Wv1 = (const float*)d_in[7];  const float* bv1 = (const float*)d_in[8];
    const float* We1 = (const float*)d_in[9];
    const float* Ws1 = (const float*)d_in[10]; const float* bs1 = (const float*)d_in[11];
    const float* lnw1 = (const float*)d_in[12]; const float* lnb1 = (const float*)d_in[13];
    const float* Wq2 = (const float*)d_in[14]; const float* bq2 = (const float*)d_in[15];
    const float* Wk2 = (const float*)d_in[16]; const float* bk2 = (const float*)d_in[17];
    const float* Wv2 = (const float*)d_in[18]; const float* bv2 = (const float*)d_in[19];
    const float* We2 = (const float*)d_in[20];
    const float* Ws2 = (const float*)d_in[21]; const float* bs2 = (const float*)d_in[22];
    const float* lnw2 = (const float*)d_in[23]; const float* lnb2 = (const float*)d_in[24];
    const float* Wo  = (const float*)d_in[25]; const float* bo  = (const float*)d_in[26];

    const int N = in_sizes[0] / IN_DIM;
    const int E = in_sizes[2];
    const int* esrc = ei;
    const int* edst = ei + E;

    char* ws = (char*)d_ws;
    size_t off = 0;
    auto alloc = [&](size_t bytes) -> char* {
        char* p = ws + off;
        off += (bytes + 255) / 256 * 256;
        return p;
    };
    int*    counts = (int*)alloc((size_t)N * 4);
    double* stats  = (double*)alloc(64);
    size_t zbytes = off;
    int*    rank   = (int*)alloc((size_t)E * 4);
    int*    offs   = (int*)alloc((size_t)(N + 1) * 4);
    int2*   edat   = (int2*)alloc((size_t)(E + 8) * 8);
    __half* xh     = (__half*)alloc((size_t)N * IN_DIM * 2);
    __half* qkvs   = (__half*)alloc((size_t)N * 1024 * 2);
    unsigned char* kv8 = (unsigned char*)alloc((size_t)N * 512);
    __half* hwork  = (__half*)alloc((size_t)N * HD * 2);
    __half* hio    = (__half*)alloc((size_t)N * HD * 2);
    __half* Wc1    = (__half*)alloc((size_t)1024 * IN_DIM * 2);
    __half* Wc2    = (__half*)alloc((size_t)1024 * HD * 2);
    __half* Wot    = (__half*)alloc((size_t)64 * HD * 2);
    float*  bc1    = (float*)alloc(1024 * 4);
    float*  bc2    = (float*)alloc(1024 * 4);

    hipMemsetAsync(d_ws, 0, zbytes, stream);

    int total4x = N * (IN_DIM / 4);
    int prepWork = total4x > E ? total4x : E;
    if (prepWork < 411648) prepWork = 411648;
    prep_k<<<(prepWork + 255) / 256, 256, 0, stream>>>(
        (const float4*)x, xh, total4x, edst, counts, rank, E,
        Wq1, Wk1, Wv1, Ws1, Wq2, Wk2, Wv2, Ws2, Wo,
        bq1, bk1, bv1, bs1, bq2, bk2, bv2, bs2,
        Wc1, Wc2, Wot, bc1, bc2);

    scan_k<<<1, 1024, 0, stream>>>(counts, offs, N);
    scatter_k<<<(E + 255) / 256, 256, 0, stream>>>(esrc, edst, eattr, offs, rank,
                                                   edat, E);

    int nbx = (N + BM - 1) / BM;
    dim3 gqkvs(nbx * 8);                              // 1-D grid for XCD swizzle
    int nGroups = (N + 3) / 4;
    int gaBlocks = nGroups < 2048 ? nGroups : 2048;   // persistent blocks (proven R8 config)
    int total4 = N * (HD / 4);
    dim3 gl((total4 / 4 + 255) / 256);
    dim3 gout((N + 127) / 128);

    // ---- layer 1 ----
    gemm_mfma<<<gqkvs, 256, 0, stream>>>(xh, Wc1, bc1, qkvs, kv8, N, IN_DIM, 1024);
    attn_k<<<gaBlocks, 256, 0, stream>>>((const uint2*)qkvs, (const uint2*)kv8, We1,
                                         hwork, edat, offs, stats, N, nGroups);
    ln_apply<<<gl, 256, 0, stream>>>((const uint2*)hwork, hio,
                                     (const float4*)lnw1, (const float4*)lnb1,
                                     stats, (double)N * HD, total4);

    // ---- layer 2 ----
    gemm_mfma<<<gqkvs, 256, 0, stream>>>(hio, Wc2, bc2, qkvs, kv8, N, HD, 1024);
    attn_k<<<gaBlocks, 256, 0, stream>>>((const uint2*)qkvs, (const uint2*)kv8, We2,
                                         hwork, edat, offs, stats + 2, N, nGroups);
    ln_apply<<<gl, 256, 0, stream>>>((const uint2*)hwork, hio,
                                     (const float4*)lnw2, (const float4*)lnb2,
                                     stats + 2, (double)N * HD, total4);

    // ---- output projection (fp32 out, dedicated 128x64 kernel) ----
    gemm_out_k<<<gout, 256, 0, stream>>>(hio, Wot, bo, (float*)d_out, N);
}

// Round 6
// 643.346 us; speedup vs baseline: 2.6124x; 2.6124x over previous
//
#include <hip/hip_runtime.h>
#include <hip/hip_fp16.h>
#include <math.h>

#define IN_DIM 128
#define HD 256
#define EPSLN 1e-5f

typedef _Float16 half8 __attribute__((ext_vector_type(8)));
typedef float f32x4 __attribute__((ext_vector_type(4)));
typedef float f32x2 __attribute__((ext_vector_type(2)));

// ---------------- helpers ----------------
__device__ inline void store4(float* p, float4 o) { *(float4*)p = o; }
__device__ inline void store4(__half* p, float4 o) {
    union { uint2 u; __half2 h[2]; } s;
    s.h[0] = __floats2half2_rn(o.x, o.y);
    s.h[1] = __floats2half2_rn(o.z, o.w);
    *(uint2*)p = s.u;
}
__device__ inline float4 h4_to_f4(uint2 u) {
    union { unsigned int w; __half2 h; } a, b;
    a.w = u.x; b.w = u.y;
    float2 lo = __half22float2(a.h), hi = __half22float2(b.h);
    return make_float4(lo.x, lo.y, hi.x, hi.y);
}
// 4 floats -> 4 packed fp8 e4m3 (OCP, gfx950 HW cvt)
__device__ inline unsigned int f4_to_fp8x4(float a, float b, float c, float d) {
    int v = 0;
    v = __builtin_amdgcn_cvt_pk_fp8_f32(a, b, v, false);
    v = __builtin_amdgcn_cvt_pk_fp8_f32(c, d, v, true);
    return (unsigned int)v;
}
__device__ inline float4 fp8x4_to_f4(unsigned int u) {
    f32x2 lo = __builtin_amdgcn_cvt_pk_f32_fp8((int)u, false);
    f32x2 hi = __builtin_amdgcn_cvt_pk_f32_fp8((int)u, true);
    return make_float4(lo.x, lo.y, hi.x, hi.y);
}

__device__ inline void async_copy16(const __half* g, _Float16* l) {
    __builtin_amdgcn_global_load_lds(
        (const __attribute__((address_space(1))) void*)g,
        (__attribute__((address_space(3))) void*)l,
        16, 0, 0);
}

// Packed output column mapping: q[0:256) | kv-interleaved[256:768) | skip[768:1024)
__device__ inline void unpermute_col(int n, int& sel, int& c) {
    if (n < 256) { sel = 0; c = n; }
    else if (n < 768) {
        int j = n - 256, chunk = j >> 3, w = j & 7;
        if (w < 4) { sel = 1; c = chunk * 4 + w; }
        else       { sel = 2; c = chunk * 4 + w - 4; }
    } else { sel = 3; c = n - 768; }
}

// ---------------- fused prep: pack x, pack weights/biases, count degrees + ranks ----
__global__ void prep_k(
    const float4* __restrict__ x, __half* __restrict__ xh, int total4,
    const int* __restrict__ dst, int* __restrict__ counts, int* __restrict__ rank, int E,
    const float* __restrict__ Wq1, const float* __restrict__ Wk1,
    const float* __restrict__ Wv1, const float* __restrict__ Ws1,
    const float* __restrict__ Wq2, const float* __restrict__ Wk2,
    const float* __restrict__ Wv2, const float* __restrict__ Ws2,
    const float* __restrict__ Wo,
    const float* __restrict__ bq1, const float* __restrict__ bk1,
    const float* __restrict__ bv1, const float* __restrict__ bs1,
    const float* __restrict__ bq2, const float* __restrict__ bk2,
    const float* __restrict__ bv2, const float* __restrict__ bs2,
    __half* __restrict__ Wc1, __half* __restrict__ Wc2, __half* __restrict__ Wot,
    float* __restrict__ bc1, float* __restrict__ bc2)
{
    int idx = blockIdx.x * 256 + threadIdx.x;
    if (idx < total4) store4(xh + (size_t)idx * 4, x[idx]);
    if (idx < E) rank[idx] = atomicAdd(&counts[dst[idx]], 1);   // rank within dst bucket
    if (idx < 131072) {
        int n = idx >> 7, k = idx & 127;
        int sel, c; unpermute_col(n, sel, c);
        const float* W = (sel == 0) ? Wq1 : (sel == 1) ? Wk1 : (sel == 2) ? Wv1 : Ws1;
        Wc1[idx] = __float2half(W[(size_t)k * 256 + c]);
    } else if (idx < 393216) {
        int j = idx - 131072;
        int n = j >> 8, k = j & 255;
        int sel, c; unpermute_col(n, sel, c);
        const float* W = (sel == 0) ? Wq2 : (sel == 1) ? Wk2 : (sel == 2) ? Wv2 : Ws2;
        Wc2[j] = __float2half(W[(size_t)k * 256 + c]);
    } else if (idx < 409600) {
        int j = idx - 393216;
        int n = j >> 8, k = j & 255;
        Wot[j] = __float2half(Wo[(size_t)k * 64 + n]);
    } else if (idx < 410624) {
        int n = idx - 409600;
        int sel, c; unpermute_col(n, sel, c);
        const float* b = (sel == 0) ? bq1 : (sel == 1) ? bk1 : (sel == 2) ? bv1 : bs1;
        bc1[n] = b[c];
    } else if (idx < 411648) {
        int n = idx - 410624;
        int sel, c; unpermute_col(n, sel, c);
        const float* b = (sel == 0) ? bq2 : (sel == 1) ? bk2 : (sel == 2) ? bv2 : bs2;
        bc2[n] = b[c];
    }
}

// ---------------- MFMA GEMM: C[M x Nc] = A[M x K] @ Wt^T + bias (f16 out) ----------------
// R13: 1-D grid + XCD-grouping swizzle (measured R4: ~44us win across both gemms).
#define BM 128
#define BN 128
#define BK 64
#define TROWB 272   // f16 out-tile row stride (bytes)

__global__ __launch_bounds__(256) void gemm_mfma(
    const __half* __restrict__ A, const __half* __restrict__ Wt,
    const float* __restrict__ bias, __half* __restrict__ C,
    unsigned char* __restrict__ kv8,
    int M, int K, int Nc)
{
    __shared__ char smem[BM * TROWB];
    _Float16* As = (_Float16*)smem;
    _Float16* Bs = (_Float16*)(smem + 16384);

    int tid = threadIdx.x;
    int lane = tid & 63, w = tid >> 6;
    int wm = w >> 1, wn = w & 1;
    int quad = lane >> 4, l16 = lane & 15;
    // XCD swizzle: nwg = nbx*8 (exact multiple of 8 XCDs)
    int nbx = (int)gridDim.x >> 3;
    int wkr = ((int)blockIdx.x & 7) * nbx + ((int)blockIdx.x >> 3);
    int row0 = (wkr >> 3) * BM;
    int col0 = (wkr & 7) * BN;

    f32x4 acc[4][4];
#pragma unroll
    for (int i = 0; i < 4; i++)
#pragma unroll
        for (int j = 0; j < 4; j++) acc[i][j] = (f32x4){0.f, 0.f, 0.f, 0.f};

    int srow = lane >> 3;
    int schunk = lane & 7;

    for (int k0 = 0; k0 < K; k0 += BK) {
#pragma unroll
        for (int t = 0; t < 4; t++) {
            int r = w * 32 + t * 8 + srow;
            int gr = row0 + r; if (gr > M - 1) gr = M - 1;
            int gchunk = schunk ^ (r & 7);
            async_copy16(&A[(size_t)gr * K + k0 + gchunk * 8], &As[(w * 32 + t * 8) * 64]);
        }
#pragma unroll
        for (int t = 0; t < 4; t++) {
            int r = w * 32 + t * 8 + srow;
            int gc = col0 + r; if (gc > Nc - 1) gc = Nc - 1;
            int gchunk = schunk ^ (r & 7);
            async_copy16(&Wt[(size_t)gc * K + k0 + gchunk * 8], &Bs[(w * 32 + t * 8) * 64]);
        }
        __syncthreads();

#pragma unroll
        for (int ks = 0; ks < 2; ks++) {
            half8 af[4], bf[4];
#pragma unroll
            for (int i = 0; i < 4; i++) {
                int ra = wm * 64 + i * 16 + l16;
                af[i] = *(half8*)&As[ra * 64 + (((ks * 4 + quad) ^ (ra & 7)) * 8)];
                int rb = wn * 64 + i * 16 + l16;
                bf[i] = *(half8*)&Bs[rb * 64 + (((ks * 4 + quad) ^ (rb & 7)) * 8)];
            }
#pragma unroll
            for (int i = 0; i < 4; i++)
#pragma unroll
                for (int j = 0; j < 4; j++)
                    acc[i][j] = __builtin_amdgcn_mfma_f32_16x16x32_f16(af[i], bf[j], acc[i][j], 0, 0, 0);
        }
        __syncthreads();
    }

#pragma unroll
    for (int j = 0; j < 4; j++) {
        int tcol = wn * 64 + j * 16 + l16;
        float bb = (col0 + tcol < Nc) ? bias[col0 + tcol] : 0.f;
#pragma unroll
        for (int i = 0; i < 4; i++) {
#pragma unroll
            for (int r = 0; r < 4; r++) {
                int trow = wm * 64 + i * 16 + quad * 4 + r;
                ((__half*)(smem + trow * TROWB))[tcol] = __float2half(acc[i][j][r] + bb);
            }
        }
    }
    __syncthreads();
    bool iskv = (col0 >= 256) && (col0 < 768);
    int crow = tid >> 4, cchunk = tid & 15;
    for (int p = 0; p < 8; p++) {
        int trow = p * 16 + crow;
        int grow = row0 + trow;
        if (grow >= M) continue;
        uint4 val = *(uint4*)(smem + trow * TROWB + cchunk * 16);
        if (iskv) {
            float4 lo = h4_to_f4(make_uint2(val.x, val.y));
            float4 hi = h4_to_f4(make_uint2(val.z, val.w));
            uint2 o8;
            o8.x = f4_to_fp8x4(lo.x, lo.y, lo.z, lo.w);
            o8.y = f4_to_fp8x4(hi.x, hi.y, hi.z, hi.w);
            *(uint2*)&kv8[(size_t)grow * 512 + (col0 - 256) + cchunk * 8] = o8;
        } else {
            *(uint4*)&C[(size_t)grow * Nc + col0 + cchunk * 8] = val;
        }
    }
}

// ---------------- output GEMM: D[M x 64] = A[M x 256] @ Wot^T + bo (fp32 out) ----------
__global__ __launch_bounds__(256) void gemm_out_k(
    const __half* __restrict__ A, const __half* __restrict__ Wot,
    const float* __restrict__ bias, float* __restrict__ D, int M)
{
    __shared__ _Float16 As[128 * 64];   // 16 KB
    __shared__ _Float16 Bs[64 * 64];    // 8 KB
    int tid = threadIdx.x;
    int lane = tid & 63, w = tid >> 6;
    int quad = lane >> 4, l16 = lane & 15;
    int row0 = blockIdx.x * 128;
    const int K = 256;

    f32x4 acc[2][4];
#pragma unroll
    for (int i = 0; i < 2; i++)
#pragma unroll
        for (int j = 0; j < 4; j++) acc[i][j] = (f32x4){0.f, 0.f, 0.f, 0.f};

    int srow = lane >> 3;
    int schunk = lane & 7;

    for (int k0 = 0; k0 < K; k0 += BK) {
#pragma unroll
        for (int t = 0; t < 4; t++) {
            int r = w * 32 + t * 8 + srow;
            int gr = row0 + r; if (gr > M - 1) gr = M - 1;
            int gchunk = schunk ^ (r & 7);
            async_copy16(&A[(size_t)gr * K + k0 + gchunk * 8], &As[(w * 32 + t * 8) * 64]);
        }
#pragma unroll
        for (int t = 0; t < 2; t++) {
            int r = w * 16 + t * 8 + srow;     // 64 weight rows
            int gchunk = schunk ^ (r & 7);
            async_copy16(&Wot[(size_t)r * K + k0 + gchunk * 8], &Bs[(w * 16 + t * 8) * 64]);
        }
        __syncthreads();

#pragma unroll
        for (int ks = 0; ks < 2; ks++) {
            half8 af[2], bf[4];
#pragma unroll
            for (int i = 0; i < 2; i++) {
                int ra = w * 32 + i * 16 + l16;
                af[i] = *(half8*)&As[ra * 64 + (((ks * 4 + quad) ^ (ra & 7)) * 8)];
            }
#pragma unroll
            for (int j = 0; j < 4; j++) {
                int rb = j * 16 + l16;
                bf[j] = *(half8*)&Bs[rb * 64 + (((ks * 4 + quad) ^ (rb & 7)) * 8)];
            }
#pragma unroll
            for (int i = 0; i < 2; i++)
#pragma unroll
                for (int j = 0; j < 4; j++)
                    acc[i][j] = __builtin_amdgcn_mfma_f32_16x16x32_f16(af[i], bf[j], acc[i][j], 0, 0, 0);
        }
        __syncthreads();
    }

#pragma unroll
    for (int i = 0; i < 2; i++) {
#pragma unroll
        for (int j = 0; j < 4; j++) {
            int gcol = j * 16 + l16;
            float bb = bias[gcol];
#pragma unroll
            for (int r = 0; r < 4; r++) {
                int grow = row0 + w * 32 + i * 16 + quad * 4 + r;
                if (grow < M) D[(size_t)grow * 64 + gcol] = acc[i][j][r] + bb;
            }
        }
    }
}

// ---------------- edge bucketing ----------------
__global__ __launch_bounds__(1024) void scan_k(const int* __restrict__ counts,
                                               int* __restrict__ offs, int n)
{
    __shared__ int wsum[16];
    __shared__ int wpre[16];
    int tid = threadIdx.x, lane = tid & 63, wid = tid >> 6;
    int per = (n + 1023) / 1024;
    int start = tid * per, end = min(start + per, n);
    int sum = 0;
    for (int i = start; i < end; i++) sum += counts[i];
    int v = sum;
#pragma unroll
    for (int d = 1; d < 64; d <<= 1) {
        int t = __shfl_up(v, (unsigned)d, 64);
        if (lane >= d) v += t;
    }
    if (lane == 63) wsum[wid] = v;
    __syncthreads();
    if (tid == 0) {
        int acc = 0;
        for (int i = 0; i < 16; i++) { wpre[i] = acc; acc += wsum[i]; }
    }
    __syncthreads();
    int pre = wpre[wid] + v - sum;
    for (int i = start; i < end; i++) { offs[i] = pre; pre += counts[i]; }
    if (end == n && start <= n) offs[n] = pre;
}

// atomic-free: position = segment offset + precomputed rank
__global__ void scatter_k(const int* __restrict__ src, const int* __restrict__ dst,
                          const float* __restrict__ attr, const int* __restrict__ offs,
                          const int* __restrict__ rank, int2* __restrict__ edat, int E)
{
    int e = blockIdx.x * 256 + threadIdx.x;
    if (e < 8) edat[E + e] = make_int2(0, 0);
    if (e < E) {
        int p = offs[dst[e]] + rank[e];
        edat[p] = make_int2(src[e], __float_as_int(attr[e]));
    }
}

// ---------------- attention: one wave per dst node, batched online softmax ----
// 2048 persistent blocks (proven R8/R10 config; do not shrink block lifetime).
// R12: batch-of-8 deferred-max softmax (one m-merge/corr-exp/rescale per batch).
// R13: within-node ping-pong + SGPR-hoisted edge metadata.
// R14: CROSS-NODE pipeline (next node's q+offs prefetch + first gather batch
// issued before current node's last COMPUTE).
// R15: REVERT the (256,8) launch-bounds pin from R14's submission — it forced
// a <=64-VGPR budget on a ~90-reg structure, spilling the ping-pong buffers
// to scratch (measured: VGPR=32, WRITE_SIZE 25MB->1.54GB, 666us, VALU 10%).
// NEVER pin min-waves on a register-hungry kernel; let the allocator float.
__global__ __launch_bounds__(256) void attn_k(
    const uint2* __restrict__ q2, const uint2* __restrict__ kv8u2,
    const float* __restrict__ We,
    __half* __restrict__ hwork, const int2* __restrict__ edat,
    const int* __restrict__ offs,
    double* __restrict__ stats, int n, int nGroups)
{
    __shared__ float4 weLds[64];
    __shared__ float red[8];
    int lane = threadIdx.x & 63;
    int wid = threadIdx.x >> 6;
    if (threadIdx.x < 64) weLds[threadIdx.x] = ((const float4*)We)[threadIdx.x];
    __syncthreads();
    float tsum = 0.f, tsq = 0.f;

    int abA[8], srA[8], abB[8], srB[8];   // SGPR: attr bits / src index
    uint2 kvA[8], kvB[8];

    int g = blockIdx.x;
    // prologue: prefetch first node's q + offs
    uint2 qraw = make_uint2(0u, 0u);
    int i0 = 0, i1 = 0;
    if (g < nGroups) {
        int node = g * 4 + wid;
        if (node < n) {
            qraw = q2[(size_t)node * 256 + lane];
            i0 = __builtin_amdgcn_readfirstlane(offs[node]);
            i1 = __builtin_amdgcn_readfirstlane(offs[node + 1]);
        }
    }
    bool carry = false, carryB = false;

    for (; g < nGroups; g += gridDim.x) {
        int node = g * 4 + wid;
        if (node >= n) continue;           // (n%4==0 in practice; kept for safety)

        // ---- prefetch NEXT node's q + offs (used a full node later) ----
        int gN = g + gridDim.x;
        uint2 qrawN = make_uint2(0u, 0u);
        int i0N = 0, i1N = 0;
        if (gN < nGroups) {
            int nodeN = gN * 4 + wid;
            qrawN = q2[(size_t)nodeN * 256 + lane];
            i0N = __builtin_amdgcn_readfirstlane(offs[nodeN]);
            i1N = __builtin_amdgcn_readfirstlane(offs[nodeN + 1]);
        }
        bool hasNext = (i0N < i1N);

        // ---- current node setup ----
        float4 we = weLds[lane];
        float4 qv = h4_to_f4(qraw);
        float qwe = qv.x * we.x + qv.y * we.y + qv.z * we.z + qv.w * we.w;
        qwe += __shfl_xor(qwe, 1);
        qwe += __shfl_xor(qwe, 2);
        qwe += __shfl_xor(qwe, 4);

        float4 accv = make_float4(0.f, 0.f, 0.f, 0.f);
        float sat = 0.f;
        float m = -INFINITY, l = 0.f;

        auto LOADB = [&](int base, int cnt, int* ab_, int* sr_, uint2* kv_) {
#pragma unroll
            for (int u = 0; u < 8; u++) {
                int2 ed = edat[base + ((u < cnt) ? u : 0)];   // clamp: dup -> L1 hit
                sr_[u] = __builtin_amdgcn_readfirstlane(ed.x);
                ab_[u] = __builtin_amdgcn_readfirstlane(ed.y);
            }
#pragma unroll
            for (int u = 0; u < 8; u++)
                kv_[u] = (kv8u2 + (size_t)(unsigned)sr_[u] * 64)[lane];
        };

        auto COMPUTE = [&](const int* ab_, const uint2* kv_, int cnt) {
            float pv[8];
#pragma unroll
            for (int u = 0; u < 8; u++) {
                float4 kvf = fp8x4_to_f4(kv_[u].x);
                float p = qv.x * kvf.x + qv.y * kvf.y + qv.z * kvf.z + qv.w * kvf.w;
                p += __shfl_xor(p, 1);
                p += __shfl_xor(p, 2);
                p += __shfl_xor(p, 4);
                p = fmaf(__int_as_float(ab_[u]), qwe, p) * 0.17677669529663687f;
                pv[u] = (u < cnt) ? p : -INFINITY;            // folds away for cnt=8
            }
            float m01 = fmaxf(pv[0], pv[1]), m23 = fmaxf(pv[2], pv[3]);
            float m45 = fmaxf(pv[4], pv[5]), m67 = fmaxf(pv[6], pv[7]);
            float pmax = fmaxf(fmaxf(m01, m23), fmaxf(m45, m67));
            float mn = fmaxf(m, pmax);
            float corr = __expf(m - mn);
            l *= corr;
            sat *= corr;
            accv.x *= corr; accv.y *= corr; accv.z *= corr; accv.w *= corr;
#pragma unroll
            for (int u = 0; u < 8; u++) {
                float wgt = __expf(pv[u] - mn);               // pad: exp(-inf)=0
                l += wgt;
                sat = fmaf(wgt, __int_as_float(ab_[u]), sat);
                float4 vv = fp8x4_to_f4(kv_[u].y);
                accv.x = fmaf(wgt, vv.x, accv.x);
                accv.y = fmaf(wgt, vv.y, accv.y);
                accv.z = fmaf(wgt, vv.z, accv.z);
                accv.w = fmaf(wgt, vv.w, accv.w);
            }
            m = mn;
        };

        bool ncarry = false, ncarryB = false;
        if (i0 < i1) {
            int i = i0;
            bool curB;
            if (carry) { curB = carryB; }
            else       { LOADB(i0, min(8, i1 - i0), abA, srA, kvA); curB = false; }
            while (true) {
                int rem = i1 - i;
                if (rem > 8) {
                    int c2 = min(8, rem - 8);
                    if (curB) LOADB(i + 8, c2, abA, srA, kvA);
                    else      LOADB(i + 8, c2, abB, srB, kvB);
                    if (curB) COMPUTE(abB, kvB, 8);
                    else      COMPUTE(abA, kvA, 8);
                    i += 8; curB = !curB;
                } else {
                    if (hasNext) {
                        int c0 = min(8, i1N - i0N);
                        if (curB) LOADB(i0N, c0, abA, srA, kvA);
                        else      LOADB(i0N, c0, abB, srB, kvB);
                        ncarry = true; ncarryB = !curB;
                    }
                    if (curB) COMPUTE(abB, kvB, rem);
                    else      COMPUTE(abA, kvA, rem);
                    break;
                }
            }
        } else {
            // degree-0 node (rare): still prefetch next node's first batch
            if (hasNext) {
                LOADB(i0N, min(8, i1N - i0N), abA, srA, kvA);
                ncarry = true; ncarryB = false;
            }
        }

        // ---- epilogue ----
        float inv = (l > 0.f) ? 1.f / l : 0.f;
        float4 sk = h4_to_f4(q2[(size_t)node * 256 + 192 + lane]);
        float4 we2 = weLds[lane];
        float sw = sat * inv;
        float4 o;
        o.x = fmaf(accv.x, inv, fmaf(sw, we2.x, sk.x));
        o.y = fmaf(accv.y, inv, fmaf(sw, we2.y, sk.y));
        o.z = fmaf(accv.z, inv, fmaf(sw, we2.z, sk.z));
        o.w = fmaf(accv.w, inv, fmaf(sw, we2.w, sk.w));
        store4(hwork + (size_t)node * 256 + lane * 4, o);
        tsum += o.x + o.y + o.z + o.w;
        tsq += o.x * o.x + o.y * o.y + o.z * o.z + o.w * o.w;

        // ---- rotate node state ----
        qraw = qrawN; i0 = i0N; i1 = i1N;
        carry = ncarry; carryB = ncarryB;
    }

#pragma unroll
    for (int d = 1; d < 64; d <<= 1) {
        tsum += __shfl_xor(tsum, d);
        tsq += __shfl_xor(tsq, d);
    }
    if (lane == 0) { red[wid] = tsum; red[4 + wid] = tsq; }
    __syncthreads();
    if (threadIdx.x == 0) {
        double s = (double)red[0] + (double)red[1] + (double)red[2] + (double)red[3];
        double sq = (double)red[4] + (double)red[5] + (double)red[6] + (double)red[7];
        atomicAdd(&stats[0], s);
        atomicAdd(&stats[1], sq);
    }
}

// ---------------- LayerNorm apply (f16 in, f16 out; 4 elems/thread) ----------------
__global__ __launch_bounds__(256) void ln_apply(
    const uint2* __restrict__ in, __half* __restrict__ out,
    const float4* __restrict__ w4, const float4* __restrict__ b4,
    const double* __restrict__ stats, double cnt, int total4)
{
    int base = (blockIdx.x * 256 + threadIdx.x) * 4;
    if (base >= total4) return;
    double mu = stats[0] / cnt;
    double var = stats[1] / cnt - mu * mu;
    if (var < 0.0) var = 0.0;
    float mean = (float)mu;
    float inv = (float)(1.0 / (sqrt(var) + (double)EPSLN));
#pragma unroll
    for (int u = 0; u < 4; u++) {
        int i = base + u;
        if (i >= total4) return;
        int c = i & 63;
        float4 xv = h4_to_f4(in[i]);
        float4 w = w4[c], b = b4[c];
        float4 o;
        o.x = fmaf((xv.x - mean) * inv, w.x, b.x);
        o.y = fmaf((xv.y - mean) * inv, w.y, b.y);
        o.z = fmaf((xv.z - mean) * inv, w.z, b.z);
        o.w = fmaf((xv.w - mean) * inv, w.w, b.w);
        o.x = o.x > 0.f ? o.x : expm1f(o.x);
        o.y = o.y > 0.f ? o.y : expm1f(o.y);
        o.z = o.z > 0.f ? o.z : expm1f(o.z);
        o.w = o.w > 0.f ? o.w : expm1f(o.w);
        store4(out + (size_t)i * 4, o);
    }
}

// ---------------- driver ----------------
extern "C" void kernel_launch(void* const* d_in, const int* in_sizes, int n_in,
                              void* d_out, int out_size, void* d_ws, size_t ws_size,
                              hipStream_t stream)
{
    const float* x      = (const float*)d_in[0];
    const int*   ei     = (const int*)d_in[1];
    const float* eattr  = (const float*)d_in[2];
    const float* Wq1 = (const float*)d_in[3];  const float* bq1 = (const float*)d_in[4];
    const float* Wk1 = (const float*)d_in[5];  const float* bk1 = (const float*)d_in[6];
    const float* Wv1 = (const float*)d_in[7];  const float* bv1 = (const float*)d_in[8];
    const float* We1 = (const float*)d_in[9];
    const float* Ws1 = (const float*)d_in[10]; const float* bs1 = (const float*)d_in[11];
    const float* lnw1 = (const float*)d_in[12]; const float* lnb1 = (const float*)d_in[13];
    const float* Wq2 = (const float*)d_in[14]; const float* bq2 = (const float*)d_in[15];
    const float* Wk2 = (const float*)d_in[16]; const float* bk2 = (const float*)d_in[17];
    const float* Wv2 = (const float*)d_in[18]; const float* bv2 = (const float*)d_in[19];
    const float* We2 = (const float*)d_in[20];
    const float* Ws2 = (const float*)d_in[21]; const float* bs2 = (const float*)d_in[22];
    const float* lnw2 = (const float*)d_in[23]; const float* lnb2 = (const float*)d_in[24];
    const float* Wo  = (const float*)d_in[25]; const float* bo  = (const float*)d_in[26];

    const int N = in_sizes[0] / IN_DIM;
    const int E = in_sizes[2];
    const int* esrc = ei;
    const int* edst = ei + E;

    char* ws = (char*)d_ws;
    size_t off = 0;
    auto alloc = [&](size_t bytes) -> char* {
        char* p = ws + off;
        off += (bytes + 255) / 256 * 256;
        return p;
    };
    int*    counts = (int*)alloc((size_t)N * 4);
    double* stats  = (double*)alloc(64);
    size_t zbytes = off;
    int*    rank   = (int*)alloc((size_t)E * 4);
    int*    offs   = (int*)alloc((size_t)(N + 1) * 4);
    int2*   edat   = (int2*)alloc((size_t)(E + 8) * 8);
    __half* xh     = (__half*)alloc((size_t)N * IN_DIM * 2);
    __half* qkvs   = (__half*)alloc((size_t)N * 1024 * 2);
    unsigned char* kv8 = (unsigned char*)alloc((size_t)N * 512);
    __half* hwork  = (__half*)alloc((size_t)N * HD * 2);
    __half* hio    = (__half*)alloc((size_t)N * HD * 2);
    __half* Wc1    = (__half*)alloc((size_t)1024 * IN_DIM * 2);
    __half* Wc2    = (__half*)alloc((size_t)1024 * HD * 2);
    __half* Wot    = (__half*)alloc((size_t)64 * HD * 2);
    float*  bc1    = (float*)alloc(1024 * 4);
    float*  bc2    = (float*)alloc(1024 * 4);

    hipMemsetAsync(d_ws, 0, zbytes, stream);

    int total4x = N * (IN_DIM / 4);
    int prepWork = total4x > E ? total4x : E;
    if (prepWork < 411648) prepWork = 411648;
    prep_k<<<(prepWork + 255) / 256, 256, 0, stream>>>(
        (const float4*)x, xh, total4x, edst, counts, rank, E,
        Wq1, Wk1, Wv1, Ws1, Wq2, Wk2, Wv2, Ws2, Wo,
        bq1, bk1, bv1, bs1, bq2, bk2, bv2, bs2,
        Wc1, Wc2, Wot, bc1, bc2);

    scan_k<<<1, 1024, 0, stream>>>(counts, offs, N);
    scatter_k<<<(E + 255) / 256, 256, 0, stream>>>(esrc, edst, eattr, offs, rank,
                                                   edat, E);

    int nbx = (N + BM - 1) / BM;
    dim3 gqkvs(nbx * 8);                              // 1-D grid for XCD swizzle
    int nGroups = (N + 3) / 4;
    int gaBlocks = nGroups < 2048 ? nGroups : 2048;   // persistent blocks (proven R8 config)
    int total4 = N * (HD / 4);
    dim3 gl((total4 / 4 + 255) / 256);
    dim3 gout((N + 127) / 128);

    // ---- layer 1 ----
    gemm_mfma<<<gqkvs, 256, 0, stream>>>(xh, Wc1, bc1, qkvs, kv8, N, IN_DIM, 1024);
    attn_k<<<gaBlocks, 256, 0, stream>>>((const uint2*)qkvs, (const uint2*)kv8, We1,
                                         hwork, edat, offs, stats, N, nGroups);
    ln_apply<<<gl, 256, 0, stream>>>((const uint2*)hwork, hio,
                                     (const float4*)lnw1, (const float4*)lnb1,
                                     stats, (double)N * HD, total4);

    // ---- layer 2 ----
    gemm_mfma<<<gqkvs, 256, 0, stream>>>(hio, Wc2, bc2, qkvs, kv8, N, HD, 1024);
    attn_k<<<gaBlocks, 256, 0, stream>>>((const uint2*)qkvs, (const uint2*)kv8, We2,
                                         hwork, edat, offs, stats + 2, N, nGroups);
    ln_apply<<<gl, 256, 0, stream>>>((const uint2*)hwork, hio,
                                     (const float4*)lnw2, (const float4*)lnb2,
                                     stats + 2, (double)N * HD, total4);

    // ---- output projection (fp32 out, dedicated 128x64 kernel) ----
    gemm_out_k<<<gout, 256, 0, stream>>>(hio, Wot, bo, (float*)d_out, N);
}

// Round 7
// 605.263 us; speedup vs baseline: 2.7767x; 1.0629x over previous
//
#include <hip/hip_runtime.h>
#include <hip/hip_fp16.h>
#include <math.h>

#define IN_DIM 128
#define HD 256
#define EPSLN 1e-5f

typedef _Float16 half8 __attribute__((ext_vector_type(8)));
typedef float f32x4 __attribute__((ext_vector_type(4)));
typedef float f32x2 __attribute__((ext_vector_type(2)));

// ---------------- helpers ----------------
__device__ inline void store4(float* p, float4 o) { *(float4*)p = o; }
__device__ inline void store4(__half* p, float4 o) {
    union { uint2 u; __half2 h[2]; } s;
    s.h[0] = __floats2half2_rn(o.x, o.y);
    s.h[1] = __floats2half2_rn(o.z, o.w);
    *(uint2*)p = s.u;
}
__device__ inline float4 h4_to_f4(uint2 u) {
    union { unsigned int w; __half2 h; } a, b;
    a.w = u.x; b.w = u.y;
    float2 lo = __half22float2(a.h), hi = __half22float2(b.h);
    return make_float4(lo.x, lo.y, hi.x, hi.y);
}
// 4 floats -> 4 packed fp8 e4m3 (OCP, gfx950 HW cvt)
__device__ inline unsigned int f4_to_fp8x4(float a, float b, float c, float d) {
    int v = 0;
    v = __builtin_amdgcn_cvt_pk_fp8_f32(a, b, v, false);
    v = __builtin_amdgcn_cvt_pk_fp8_f32(c, d, v, true);
    return (unsigned int)v;
}
__device__ inline float4 fp8x4_to_f4(unsigned int u) {
    f32x2 lo = __builtin_amdgcn_cvt_pk_f32_fp8((int)u, false);
    f32x2 hi = __builtin_amdgcn_cvt_pk_f32_fp8((int)u, true);
    return make_float4(lo.x, lo.y, hi.x, hi.y);
}

__device__ inline void async_copy16(const __half* g, _Float16* l) {
    __builtin_amdgcn_global_load_lds(
        (const __attribute__((address_space(1))) void*)g,
        (__attribute__((address_space(3))) void*)l,
        16, 0, 0);
}

// Packed output column mapping: q[0:256) | kv-interleaved[256:768) | skip[768:1024)
__device__ inline void unpermute_col(int n, int& sel, int& c) {
    if (n < 256) { sel = 0; c = n; }
    else if (n < 768) {
        int j = n - 256, chunk = j >> 3, w = j & 7;
        if (w < 4) { sel = 1; c = chunk * 4 + w; }
        else       { sel = 2; c = chunk * 4 + w - 4; }
    } else { sel = 3; c = n - 768; }
}

// ---------------- fused prep: pack x, pack weights/biases, count degrees + ranks ----
__global__ void prep_k(
    const float4* __restrict__ x, __half* __restrict__ xh, int total4,
    const int* __restrict__ dst, int* __restrict__ counts, int* __restrict__ rank, int E,
    const float* __restrict__ Wq1, const float* __restrict__ Wk1,
    const float* __restrict__ Wv1, const float* __restrict__ Ws1,
    const float* __restrict__ Wq2, const float* __restrict__ Wk2,
    const float* __restrict__ Wv2, const float* __restrict__ Ws2,
    const float* __restrict__ Wo,
    const float* __restrict__ bq1, const float* __restrict__ bk1,
    const float* __restrict__ bv1, const float* __restrict__ bs1,
    const float* __restrict__ bq2, const float* __restrict__ bk2,
    const float* __restrict__ bv2, const float* __restrict__ bs2,
    __half* __restrict__ Wc1, __half* __restrict__ Wc2, __half* __restrict__ Wot,
    float* __restrict__ bc1, float* __restrict__ bc2)
{
    int idx = blockIdx.x * 256 + threadIdx.x;
    if (idx < total4) store4(xh + (size_t)idx * 4, x[idx]);
    if (idx < E) rank[idx] = atomicAdd(&counts[dst[idx]], 1);   // rank within dst bucket
    if (idx < 131072) {
        int n = idx >> 7, k = idx & 127;
        int sel, c; unpermute_col(n, sel, c);
        const float* W = (sel == 0) ? Wq1 : (sel == 1) ? Wk1 : (sel == 2) ? Wv1 : Ws1;
        Wc1[idx] = __float2half(W[(size_t)k * 256 + c]);
    } else if (idx < 393216) {
        int j = idx - 131072;
        int n = j >> 8, k = j & 255;
        int sel, c; unpermute_col(n, sel, c);
        const float* W = (sel == 0) ? Wq2 : (sel == 1) ? Wk2 : (sel == 2) ? Wv2 : Ws2;
        Wc2[j] = __float2half(W[(size_t)k * 256 + c]);
    } else if (idx < 409600) {
        int j = idx - 393216;
        int n = j >> 8, k = j & 255;
        Wot[j] = __float2half(Wo[(size_t)k * 64 + n]);
    } else if (idx < 410624) {
        int n = idx - 409600;
        int sel, c; unpermute_col(n, sel, c);
        const float* b = (sel == 0) ? bq1 : (sel == 1) ? bk1 : (sel == 2) ? bv1 : bs1;
        bc1[n] = b[c];
    } else if (idx < 411648) {
        int n = idx - 410624;
        int sel, c; unpermute_col(n, sel, c);
        const float* b = (sel == 0) ? bq2 : (sel == 1) ? bk2 : (sel == 2) ? bv2 : bs2;
        bc2[n] = b[c];
    }
}

// ---------------- MFMA GEMM: C[M x Nc] = A[M x K] @ Wt^T + bias (f16 out) ----------------
// R13: 1-D grid + XCD-grouping swizzle (measured R4: ~44us win across both gemms).
#define BM 128
#define BN 128
#define BK 64
#define TROWB 272   // f16 out-tile row stride (bytes)

__global__ __launch_bounds__(256) void gemm_mfma(
    const __half* __restrict__ A, const __half* __restrict__ Wt,
    const float* __restrict__ bias, __half* __restrict__ C,
    unsigned char* __restrict__ kv8,
    int M, int K, int Nc)
{
    __shared__ char smem[BM * TROWB];
    _Float16* As = (_Float16*)smem;
    _Float16* Bs = (_Float16*)(smem + 16384);

    int tid = threadIdx.x;
    int lane = tid & 63, w = tid >> 6;
    int wm = w >> 1, wn = w & 1;
    int quad = lane >> 4, l16 = lane & 15;
    // XCD swizzle: nwg = nbx*8 (exact multiple of 8 XCDs)
    int nbx = (int)gridDim.x >> 3;
    int wkr = ((int)blockIdx.x & 7) * nbx + ((int)blockIdx.x >> 3);
    int row0 = (wkr >> 3) * BM;
    int col0 = (wkr & 7) * BN;

    f32x4 acc[4][4];
#pragma unroll
    for (int i = 0; i < 4; i++)
#pragma unroll
        for (int j = 0; j < 4; j++) acc[i][j] = (f32x4){0.f, 0.f, 0.f, 0.f};

    int srow = lane >> 3;
    int schunk = lane & 7;

    for (int k0 = 0; k0 < K; k0 += BK) {
#pragma unroll
        for (int t = 0; t < 4; t++) {
            int r = w * 32 + t * 8 + srow;
            int gr = row0 + r; if (gr > M - 1) gr = M - 1;
            int gchunk = schunk ^ (r & 7);
            async_copy16(&A[(size_t)gr * K + k0 + gchunk * 8], &As[(w * 32 + t * 8) * 64]);
        }
#pragma unroll
        for (int t = 0; t < 4; t++) {
            int r = w * 32 + t * 8 + srow;
            int gc = col0 + r; if (gc > Nc - 1) gc = Nc - 1;
            int gchunk = schunk ^ (r & 7);
            async_copy16(&Wt[(size_t)gc * K + k0 + gchunk * 8], &Bs[(w * 32 + t * 8) * 64]);
        }
        __syncthreads();

#pragma unroll
        for (int ks = 0; ks < 2; ks++) {
            half8 af[4], bf[4];
#pragma unroll
            for (int i = 0; i < 4; i++) {
                int ra = wm * 64 + i * 16 + l16;
                af[i] = *(half8*)&As[ra * 64 + (((ks * 4 + quad) ^ (ra & 7)) * 8)];
                int rb = wn * 64 + i * 16 + l16;
                bf[i] = *(half8*)&Bs[rb * 64 + (((ks * 4 + quad) ^ (rb & 7)) * 8)];
            }
#pragma unroll
            for (int i = 0; i < 4; i++)
#pragma unroll
                for (int j = 0; j < 4; j++)
                    acc[i][j] = __builtin_amdgcn_mfma_f32_16x16x32_f16(af[i], bf[j], acc[i][j], 0, 0, 0);
        }
        __syncthreads();
    }

#pragma unroll
    for (int j = 0; j < 4; j++) {
        int tcol = wn * 64 + j * 16 + l16;
        float bb = (col0 + tcol < Nc) ? bias[col0 + tcol] : 0.f;
#pragma unroll
        for (int i = 0; i < 4; i++) {
#pragma unroll
            for (int r = 0; r < 4; r++) {
                int trow = wm * 64 + i * 16 + quad * 4 + r;
                ((__half*)(smem + trow * TROWB))[tcol] = __float2half(acc[i][j][r] + bb);
            }
        }
    }
    __syncthreads();
    bool iskv = (col0 >= 256) && (col0 < 768);
    int crow = tid >> 4, cchunk = tid & 15;
    for (int p = 0; p < 8; p++) {
        int trow = p * 16 + crow;
        int grow = row0 + trow;
        if (grow >= M) continue;
        uint4 val = *(uint4*)(smem + trow * TROWB + cchunk * 16);
        if (iskv) {
            float4 lo = h4_to_f4(make_uint2(val.x, val.y));
            float4 hi = h4_to_f4(make_uint2(val.z, val.w));
            uint2 o8;
            o8.x = f4_to_fp8x4(lo.x, lo.y, lo.z, lo.w);
            o8.y = f4_to_fp8x4(hi.x, hi.y, hi.z, hi.w);
            *(uint2*)&kv8[(size_t)grow * 512 + (col0 - 256) + cchunk * 8] = o8;
        } else {
            *(uint4*)&C[(size_t)grow * Nc + col0 + cchunk * 8] = val;
        }
    }
}

// ---------------- output GEMM with fused LN2+ELU on A:  D = elu(LN(hwork)) @ Wot^T + bo ----
// R16: ln_apply #2's only consumer was this kernel; hio was a 51MB write+read
// round-trip + one launch. A is reg-staged (global->LN->ELU->f16->ds_write to
// the same XOR-swizzled LDS slots the async copy used); Wot stays async.
// Numerics identical to ln_apply (f32 LN -> ELU -> f16 round, then MFMA).
__global__ __launch_bounds__(256) void gemm_out_ln_k(
    const __half* __restrict__ A,            // hwork (pre-LN), N x 256 f16
    const __half* __restrict__ Wot,
    const float* __restrict__ lnw, const float* __restrict__ lnb,
    const double* __restrict__ stats, double cnt,
    const float* __restrict__ bias, float* __restrict__ D, int M)
{
    __shared__ _Float16 As[128 * 64];   // 16 KB
    __shared__ _Float16 Bs[64 * 64];    // 8 KB
    int tid = threadIdx.x;
    int lane = tid & 63, w = tid >> 6;
    int quad = lane >> 4, l16 = lane & 15;
    int row0 = blockIdx.x * 128;
    const int K = 256;

    double mu = stats[0] / cnt;
    double var = stats[1] / cnt - mu * mu;
    if (var < 0.0) var = 0.0;
    float mean = (float)mu;
    float inv = (float)(1.0 / (sqrt(var) + (double)EPSLN));

    f32x4 acc[2][4];
#pragma unroll
    for (int i = 0; i < 2; i++)
#pragma unroll
        for (int j = 0; j < 4; j++) acc[i][j] = (f32x4){0.f, 0.f, 0.f, 0.f};

    int srow = lane >> 3;
    int schunk = lane & 7;

    for (int k0 = 0; k0 < K; k0 += BK) {
#pragma unroll
        for (int t = 0; t < 4; t++) {
            int r = w * 32 + t * 8 + srow;
            int gr = row0 + r; if (gr > M - 1) gr = M - 1;
            int gchunk = schunk ^ (r & 7);
            int c0 = k0 + gchunk * 8;
            uint4 raw = *(const uint4*)&A[(size_t)gr * K + c0];
            float4 v0 = h4_to_f4(make_uint2(raw.x, raw.y));
            float4 v1 = h4_to_f4(make_uint2(raw.z, raw.w));
            float4 w0 = *(const float4*)&lnw[c0], w1 = *(const float4*)&lnw[c0 + 4];
            float4 b0 = *(const float4*)&lnb[c0], b1 = *(const float4*)&lnb[c0 + 4];
            float4 o0, o1;
            o0.x = fmaf((v0.x - mean) * inv, w0.x, b0.x);
            o0.y = fmaf((v0.y - mean) * inv, w0.y, b0.y);
            o0.z = fmaf((v0.z - mean) * inv, w0.z, b0.z);
            o0.w = fmaf((v0.w - mean) * inv, w0.w, b0.w);
            o1.x = fmaf((v1.x - mean) * inv, w1.x, b1.x);
            o1.y = fmaf((v1.y - mean) * inv, w1.y, b1.y);
            o1.z = fmaf((v1.z - mean) * inv, w1.z, b1.z);
            o1.w = fmaf((v1.w - mean) * inv, w1.w, b1.w);
            o0.x = o0.x > 0.f ? o0.x : expm1f(o0.x);
            o0.y = o0.y > 0.f ? o0.y : expm1f(o0.y);
            o0.z = o0.z > 0.f ? o0.z : expm1f(o0.z);
            o0.w = o0.w > 0.f ? o0.w : expm1f(o0.w);
            o1.x = o1.x > 0.f ? o1.x : expm1f(o1.x);
            o1.y = o1.y > 0.f ? o1.y : expm1f(o1.y);
            o1.z = o1.z > 0.f ? o1.z : expm1f(o1.z);
            o1.w = o1.w > 0.f ? o1.w : expm1f(o1.w);
            union { uint2 u[2]; uint4 q; } pk;
            { union { uint2 u; __half2 h[2]; } s;
              s.h[0] = __floats2half2_rn(o0.x, o0.y);
              s.h[1] = __floats2half2_rn(o0.z, o0.w);
              pk.u[0] = s.u; }
            { union { uint2 u; __half2 h[2]; } s;
              s.h[0] = __floats2half2_rn(o1.x, o1.y);
              s.h[1] = __floats2half2_rn(o1.z, o1.w);
              pk.u[1] = s.u; }
            *(uint4*)&As[(w * 32 + t * 8 + srow) * 64 + schunk * 8] = pk.q;
        }
#pragma unroll
        for (int t = 0; t < 2; t++) {
            int r = w * 16 + t * 8 + srow;     // 64 weight rows
            int gchunk = schunk ^ (r & 7);
            async_copy16(&Wot[(size_t)r * K + k0 + gchunk * 8], &Bs[(w * 16 + t * 8) * 64]);
        }
        __syncthreads();

#pragma unroll
        for (int ks = 0; ks < 2; ks++) {
            half8 af[2], bf[4];
#pragma unroll
            for (int i = 0; i < 2; i++) {
                int ra = w * 32 + i * 16 + l16;
                af[i] = *(half8*)&As[ra * 64 + (((ks * 4 + quad) ^ (ra & 7)) * 8)];
            }
#pragma unroll
            for (int j = 0; j < 4; j++) {
                int rb = j * 16 + l16;
                bf[j] = *(half8*)&Bs[rb * 64 + (((ks * 4 + quad) ^ (rb & 7)) * 8)];
            }
#pragma unroll
            for (int i = 0; i < 2; i++)
#pragma unroll
                for (int j = 0; j < 4; j++)
                    acc[i][j] = __builtin_amdgcn_mfma_f32_16x16x32_f16(af[i], bf[j], acc[i][j], 0, 0, 0);
        }
        __syncthreads();
    }

#pragma unroll
    for (int i = 0; i < 2; i++) {
#pragma unroll
        for (int j = 0; j < 4; j++) {
            int gcol = j * 16 + l16;
            float bb = bias[gcol];
#pragma unroll
            for (int r = 0; r < 4; r++) {
                int grow = row0 + w * 32 + i * 16 + quad * 4 + r;
                if (grow < M) D[(size_t)grow * 64 + gcol] = acc[i][j][r] + bb;
            }
        }
    }
}

// ---------------- edge bucketing ----------------
__global__ __launch_bounds__(1024) void scan_k(const int* __restrict__ counts,
                                               int* __restrict__ offs, int n)
{
    __shared__ int wsum[16];
    __shared__ int wpre[16];
    int tid = threadIdx.x, lane = tid & 63, wid = tid >> 6;
    int per = (n + 1023) / 1024;
    int start = tid * per, end = min(start + per, n);
    int sum = 0;
    for (int i = start; i < end; i++) sum += counts[i];
    int v = sum;
#pragma unroll
    for (int d = 1; d < 64; d <<= 1) {
        int t = __shfl_up(v, (unsigned)d, 64);
        if (lane >= d) v += t;
    }
    if (lane == 63) wsum[wid] = v;
    __syncthreads();
    if (tid == 0) {
        int acc = 0;
        for (int i = 0; i < 16; i++) { wpre[i] = acc; acc += wsum[i]; }
    }
    __syncthreads();
    int pre = wpre[wid] + v - sum;
    for (int i = start; i < end; i++) { offs[i] = pre; pre += counts[i]; }
    if (end == n && start <= n) offs[n] = pre;
}

// atomic-free: position = segment offset + precomputed rank
// Pads 8 entries past the end so attn tail batches can overrun safely.
__global__ void scatter_k(const int* __restrict__ src, const int* __restrict__ dst,
                          const float* __restrict__ attr, const int* __restrict__ offs,
                          const int* __restrict__ rank, int2* __restrict__ edat, int E)
{
    int e = blockIdx.x * 256 + threadIdx.x;
    if (e < 8) edat[E + e] = make_int2(0, 0);
    if (e < E) {
        int p = offs[dst[e]] + rank[e];
        edat[p] = make_int2(src[e], __float_as_int(attr[e]));
    }
}

// ---------------- attention: one wave per dst node, batched online softmax ----
// R4-MEASURED VERSION (108us, VGPR=64, occ 35%) — do not touch without A/B.
// 2048 persistent blocks; batch-of-8 deferred-max softmax; within-node
// ping-pong prefetch; SGPR-hoisted edge metadata via readfirstlane.
// HARD CONSTRAINT (measured R5/R6): VGPR must stay <= 64. 8 waves/SIMD fit the
// 512-reg pool at exactly 64; kernel is TLP-limited (runtime ~ 1/waves).
// Cross-node pipelining (+12 VGPR) measured SLOWER (137us) — retired.
__global__ __launch_bounds__(256) void attn_k(
    const uint2* __restrict__ q2, const uint2* __restrict__ kv8u2,
    const float* __restrict__ We,
    __half* __restrict__ hwork, const int2* __restrict__ edat,
    const int* __restrict__ offs,
    double* __restrict__ stats, int n, int nGroups)
{
    int lane = threadIdx.x & 63;
    int wid = threadIdx.x >> 6;
    float4 we = ((const float4*)We)[lane];
    float tsum = 0.f, tsq = 0.f;

    for (int g = blockIdx.x; g < nGroups; g += gridDim.x) {
        int node = g * 4 + wid;
        if (node >= n) continue;
        float4 qv = h4_to_f4(q2[(size_t)node * 256 + lane]);
        float qwe = qv.x * we.x + qv.y * we.y + qv.z * we.z + qv.w * we.w;
        qwe += __shfl_xor(qwe, 1);
        qwe += __shfl_xor(qwe, 2);
        qwe += __shfl_xor(qwe, 4);

        float4 accv = make_float4(0.f, 0.f, 0.f, 0.f);
        float sat = 0.f;
        float m = -INFINITY, l = 0.f;
        int i0 = __builtin_amdgcn_readfirstlane(offs[node]);
        int i1 = __builtin_amdgcn_readfirstlane(offs[node + 1]);

        int abA[8], srA[8], abB[8], srB[8];   // SGPR: attr bits / src index
        uint2 kvA[8], kvB[8];

        auto LOADB = [&](int base, int* ab_, int* sr_, uint2* kv_) {
#pragma unroll
            for (int u = 0; u < 8; u++) {
                int2 ed = edat[base + u];                     // uniform addr
                sr_[u] = __builtin_amdgcn_readfirstlane(ed.x);
                ab_[u] = __builtin_amdgcn_readfirstlane(ed.y);
            }
#pragma unroll
            for (int u = 0; u < 8; u++)
                kv_[u] = (kv8u2 + (size_t)(unsigned)sr_[u] * 64)[lane];
        };

        auto COMPUTE = [&](const int* ab_, const uint2* kv_, int cnt) {
            float pv[8];
#pragma unroll
            for (int u = 0; u < 8; u++) {
                float4 kvf = fp8x4_to_f4(kv_[u].x);
                float p = qv.x * kvf.x + qv.y * kvf.y + qv.z * kvf.z + qv.w * kvf.w;
                p += __shfl_xor(p, 1);
                p += __shfl_xor(p, 2);
                p += __shfl_xor(p, 4);
                p = fmaf(__int_as_float(ab_[u]), qwe, p) * 0.17677669529663687f;
                pv[u] = (u < cnt) ? p : -INFINITY;            // folds away for cnt=8
            }
            float m01 = fmaxf(pv[0], pv[1]), m23 = fmaxf(pv[2], pv[3]);
            float m45 = fmaxf(pv[4], pv[5]), m67 = fmaxf(pv[6], pv[7]);
            float pmax = fmaxf(fmaxf(m01, m23), fmaxf(m45, m67));
            float mn = fmaxf(m, pmax);
            float corr = __expf(m - mn);
            l *= corr;
            sat *= corr;
            accv.x *= corr; accv.y *= corr; accv.z *= corr; accv.w *= corr;
#pragma unroll
            for (int u = 0; u < 8; u++) {
                float wgt = __expf(pv[u] - mn);               // pad: exp(-inf)=0
                l += wgt;
                sat = fmaf(wgt, __int_as_float(ab_[u]), sat);
                float4 vv = fp8x4_to_f4(kv_[u].y);
                accv.x = fmaf(wgt, vv.x, accv.x);
                accv.y = fmaf(wgt, vv.y, accv.y);
                accv.z = fmaf(wgt, vv.z, accv.z);
                accv.w = fmaf(wgt, vv.w, accv.w);
            }
            m = mn;
        };

        if (i0 < i1) {
            int i = i0;
            bool curB;
            LOADB(i0, abA, srA, kvA); curB = false;
            while (true) {
                int rem = i1 - i;
                if (rem > 8) {
                    if (curB) LOADB(i + 8, abA, srA, kvA);
                    else      LOADB(i + 8, abB, srB, kvB);
                    if (curB) COMPUTE(abB, kvB, 8);
                    else      COMPUTE(abA, kvA, 8);
                    i += 8; curB = !curB;
                } else {
                    if (curB) COMPUTE(abB, kvB, rem);
                    else      COMPUTE(abA, kvA, rem);
                    break;
                }
            }
        }

        float inv = (l > 0.f) ? 1.f / l : 0.f;
        float4 sk = h4_to_f4(q2[(size_t)node * 256 + 192 + lane]);
        float sw = sat * inv;
        float4 o;
        o.x = fmaf(accv.x, inv, fmaf(sw, we.x, sk.x));
        o.y = fmaf(accv.y, inv, fmaf(sw, we.y, sk.y));
        o.z = fmaf(accv.z, inv, fmaf(sw, we.z, sk.z));
        o.w = fmaf(accv.w, inv, fmaf(sw, we.w, sk.w));
        store4(hwork + (size_t)node * 256 + lane * 4, o);
        tsum += o.x + o.y + o.z + o.w;
        tsq += o.x * o.x + o.y * o.y + o.z * o.z + o.w * o.w;
    }

#pragma unroll
    for (int d = 1; d < 64; d <<= 1) {
        tsum += __shfl_xor(tsum, d);
        tsq += __shfl_xor(tsq, d);
    }
    __shared__ float red[8];
    if (lane == 0) { red[wid] = tsum; red[4 + wid] = tsq; }
    __syncthreads();
    if (threadIdx.x == 0) {
        double s = (double)red[0] + (double)red[1] + (double)red[2] + (double)red[3];
        double sq = (double)red[4] + (double)red[5] + (double)red[6] + (double)red[7];
        atomicAdd(&stats[0], s);
        atomicAdd(&stats[1], sq);
    }
}

// ---------------- LayerNorm apply (f16 in, f16 out; 4 elems/thread) ----------------
__global__ __launch_bounds__(256) void ln_apply(
    const uint2* __restrict__ in, __half* __restrict__ out,
    const float4* __restrict__ w4, const float4* __restrict__ b4,
    const double* __restrict__ stats, double cnt, int total4)
{
    int base = (blockIdx.x * 256 + threadIdx.x) * 4;
    if (base >= total4) return;
    double mu = stats[0] / cnt;
    double var = stats[1] / cnt - mu * mu;
    if (var < 0.0) var = 0.0;
    float mean = (float)mu;
    float inv = (float)(1.0 / (sqrt(var) + (double)EPSLN));
#pragma unroll
    for (int u = 0; u < 4; u++) {
        int i = base + u;
        if (i >= total4) return;
        int c = i & 63;
        float4 xv = h4_to_f4(in[i]);
        float4 w = w4[c], b = b4[c];
        float4 o;
        o.x = fmaf((xv.x - mean) * inv, w.x, b.x);
        o.y = fmaf((xv.y - mean) * inv, w.y, b.y);
        o.z = fmaf((xv.z - mean) * inv, w.z, b.z);
        o.w = fmaf((xv.w - mean) * inv, w.w, b.w);
        o.x = o.x > 0.f ? o.x : expm1f(o.x);
        o.y = o.y > 0.f ? o.y : expm1f(o.y);
        o.z = o.z > 0.f ? o.z : expm1f(o.z);
        o.w = o.w > 0.f ? o.w : expm1f(o.w);
        store4(out + (size_t)i * 4, o);
    }
}

// ---------------- driver ----------------
extern "C" void kernel_launch(void* const* d_in, const int* in_sizes, int n_in,
                              void* d_out, int out_size, void* d_ws, size_t ws_size,
                              hipStream_t stream)
{
    const float* x      = (const float*)d_in[0];
    const int*   ei     = (const int*)d_in[1];
    const float* eattr  = (const float*)d_in[2];
    const float* Wq1 = (const float*)d_in[3];  const float* bq1 = (const float*)d_in[4];
    const float* Wk1 = (const float*)d_in[5];  const float* bk1 = (const float*)d_in[6];
    const float* Wv1 = (const float*)d_in[7];  const float* bv1 = (const float*)d_in[8];
    const float* We1 = (const float*)d_in[9];
    const float* Ws1 = (const float*)d_in[10]; const float* bs1 = (const float*)d_in[11];
    const float* lnw1 = (const float*)d_in[12]; const float* lnb1 = (const float*)d_in[13];
    const float* Wq2 = (const float*)d_in[14]; const float* bq2 = (const float*)d_in[15];
    const float* Wk2 = (const float*)d_in[16]; const float* bk2 = (const float*)d_in[17];
    const float* Wv2 = (const float*)d_in[18]; const float* bv2 = (const float*)d_in[19];
    const float* We2 = (const float*)d_in[20];
    const float* Ws2 = (const float*)d_in[21]; const float* bs2 = (const float*)d_in[22];
    const float* lnw2 = (const float*)d_in[23]; const float* lnb2 = (const float*)d_in[24];
    const float* Wo  = (const float*)d_in[25]; const float* bo  = (const float*)d_in[26];

    const int N = in_sizes[0] / IN_DIM;
    const int E = in_sizes[2];
    const int* esrc = ei;
    const int* edst = ei + E;

    char* ws = (char*)d_ws;
    size_t off = 0;
    auto alloc = [&](size_t bytes) -> char* {
        char* p = ws + off;
        off += (bytes + 255) / 256 * 256;
        return p;
    };
    int*    counts = (int*)alloc((size_t)N * 4);
    double* stats  = (double*)alloc(64);
    size_t zbytes = off;
    int*    rank   = (int*)alloc((size_t)E * 4);
    int*    offs   = (int*)alloc((size_t)(N + 1) * 4);
    int2*   edat   = (int2*)alloc((size_t)(E + 8) * 8);
    __half* xh     = (__half*)alloc((size_t)N * IN_DIM * 2);
    __half* qkvs   = (__half*)alloc((size_t)N * 1024 * 2);
    unsigned char* kv8 = (unsigned char*)alloc((size_t)N * 512);
    __half* hwork  = (__half*)alloc((size_t)N * HD * 2);
    __half* hio    = (__half*)alloc((size_t)N * HD * 2);
    __half* Wc1    = (__half*)alloc((size_t)1024 * IN_DIM * 2);
    __half* Wc2    = (__half*)alloc((size_t)1024 * HD * 2);
    __half* Wot    = (__half*)alloc((size_t)64 * HD * 2);
    float*  bc1    = (float*)alloc(1024 * 4);
    float*  bc2    = (float*)alloc(1024 * 4);

    hipMemsetAsync(d_ws, 0, zbytes, stream);

    int total4x = N * (IN_DIM / 4);
    int prepWork = total4x > E ? total4x : E;
    if (prepWork < 411648) prepWork = 411648;
    prep_k<<<(prepWork + 255) / 256, 256, 0, stream>>>(
        (const float4*)x, xh, total4x, edst, counts, rank, E,
        Wq1, Wk1, Wv1, Ws1, Wq2, Wk2, Wv2, Ws2, Wo,
        bq1, bk1, bv1, bs1, bq2, bk2, bv2, bs2,
        Wc1, Wc2, Wot, bc1, bc2);

    scan_k<<<1, 1024, 0, stream>>>(counts, offs, N);
    scatter_k<<<(E + 255) / 256, 256, 0, stream>>>(esrc, edst, eattr, offs, rank,
                                                   edat, E);

    int nbx = (N + BM - 1) / BM;
    dim3 gqkvs(nbx * 8);                              // 1-D grid for XCD swizzle
    int nGroups = (N + 3) / 4;
    int gaBlocks = nGroups < 2048 ? nGroups : 2048;   // persistent blocks (proven R8 config)
    int total4 = N * (HD / 4);
    dim3 gl((total4 / 4 + 255) / 256);
    dim3 gout((N + 127) / 128);

    // ---- layer 1 ----
    gemm_mfma<<<gqkvs, 256, 0, stream>>>(xh, Wc1, bc1, qkvs, kv8, N, IN_DIM, 1024);
    attn_k<<<gaBlocks, 256, 0, stream>>>((const uint2*)qkvs, (const uint2*)kv8, We1,
                                         hwork, edat, offs, stats, N, nGroups);
    ln_apply<<<gl, 256, 0, stream>>>((const uint2*)hwork, hio,
                                     (const float4*)lnw1, (const float4*)lnb1,
                                     stats, (double)N * HD, total4);

    // ---- layer 2 ----
    gemm_mfma<<<gqkvs, 256, 0, stream>>>(hio, Wc2, bc2, qkvs, kv8, N, HD, 1024);
    attn_k<<<gaBlocks, 256, 0, stream>>>((const uint2*)qkvs, (const uint2*)kv8, We2,
                                         hwork, edat, offs, stats + 2, N, nGroups);

    // ---- output projection with fused LN2+ELU (fp32 out) ----
    gemm_out_ln_k<<<gout, 256, 0, stream>>>(hwork, Wot, lnw2, lnb2,
                                            stats + 2, (double)N * HD,
                                            bo, (float*)d_out, N);
}

// Round 9
// 575.782 us; speedup vs baseline: 2.9189x; 1.0512x over previous
//
#include <hip/hip_runtime.h>
#include <hip/hip_fp16.h>
#include <math.h>

#define IN_DIM 128
#define HD 256
#define EPSLN 1e-5f

typedef _Float16 half8 __attribute__((ext_vector_type(8)));
typedef float f32x4 __attribute__((ext_vector_type(4)));
typedef float f32x2 __attribute__((ext_vector_type(2)));

// ---------------- helpers ----------------
__device__ inline void store4(float* p, float4 o) { *(float4*)p = o; }
__device__ inline void store4(__half* p, float4 o) {
    union { uint2 u; __half2 h[2]; } s;
    s.h[0] = __floats2half2_rn(o.x, o.y);
    s.h[1] = __floats2half2_rn(o.z, o.w);
    *(uint2*)p = s.u;
}
__device__ inline float4 h4_to_f4(uint2 u) {
    union { unsigned int w; __half2 h; } a, b;
    a.w = u.x; b.w = u.y;
    float2 lo = __half22float2(a.h), hi = __half22float2(b.h);
    return make_float4(lo.x, lo.y, hi.x, hi.y);
}
// 4 floats -> 4 packed fp8 e4m3 (OCP, gfx950 HW cvt)
__device__ inline unsigned int f4_to_fp8x4(float a, float b, float c, float d) {
    int v = 0;
    v = __builtin_amdgcn_cvt_pk_fp8_f32(a, b, v, false);
    v = __builtin_amdgcn_cvt_pk_fp8_f32(c, d, v, true);
    return (unsigned int)v;
}
__device__ inline float4 fp8x4_to_f4(unsigned int u) {
    f32x2 lo = __builtin_amdgcn_cvt_pk_f32_fp8((int)u, false);
    f32x2 hi = __builtin_amdgcn_cvt_pk_f32_fp8((int)u, true);
    return make_float4(lo.x, lo.y, hi.x, hi.y);
}

__device__ inline void async_copy16(const __half* g, _Float16* l) {
    __builtin_amdgcn_global_load_lds(
        (const __attribute__((address_space(1))) void*)g,
        (__attribute__((address_space(3))) void*)l,
        16, 0, 0);
}

// Packed output column mapping: q[0:256) | kv-interleaved[256:768) | skip[768:1024)
__device__ inline void unpermute_col(int n, int& sel, int& c) {
    if (n < 256) { sel = 0; c = n; }
    else if (n < 768) {
        int j = n - 256, chunk = j >> 3, w = j & 7;
        if (w < 4) { sel = 1; c = chunk * 4 + w; }
        else       { sel = 2; c = chunk * 4 + w - 4; }
    } else { sel = 3; c = n - 768; }
}

// ---------------- fused prep: pack x, pack weights/biases, count degrees + ranks ----
__global__ void prep_k(
    const float4* __restrict__ x, __half* __restrict__ xh, int total4,
    const int* __restrict__ dst, int* __restrict__ counts, int* __restrict__ rank, int E,
    const float* __restrict__ Wq1, const float* __restrict__ Wk1,
    const float* __restrict__ Wv1, const float* __restrict__ Ws1,
    const float* __restrict__ Wq2, const float* __restrict__ Wk2,
    const float* __restrict__ Wv2, const float* __restrict__ Ws2,
    const float* __restrict__ Wo,
    const float* __restrict__ bq1, const float* __restrict__ bk1,
    const float* __restrict__ bv1, const float* __restrict__ bs1,
    const float* __restrict__ bq2, const float* __restrict__ bk2,
    const float* __restrict__ bv2, const float* __restrict__ bs2,
    __half* __restrict__ Wc1, __half* __restrict__ Wc2, __half* __restrict__ Wot,
    float* __restrict__ bc1, float* __restrict__ bc2)
{
    int idx = blockIdx.x * 256 + threadIdx.x;
    if (idx < total4) store4(xh + (size_t)idx * 4, x[idx]);
    if (idx < E) rank[idx] = atomicAdd(&counts[dst[idx]], 1);   // rank within dst bucket
    if (idx < 131072) {
        int n = idx >> 7, k = idx & 127;
        int sel, c; unpermute_col(n, sel, c);
        const float* W = (sel == 0) ? Wq1 : (sel == 1) ? Wk1 : (sel == 2) ? Wv1 : Ws1;
        Wc1[idx] = __float2half(W[(size_t)k * 256 + c]);
    } else if (idx < 393216) {
        int j = idx - 131072;
        int n = j >> 8, k = j & 255;
        int sel, c; unpermute_col(n, sel, c);
        const float* W = (sel == 0) ? Wq2 : (sel == 1) ? Wk2 : (sel == 2) ? Wv2 : Ws2;
        Wc2[j] = __float2half(W[(size_t)k * 256 + c]);
    } else if (idx < 409600) {
        int j = idx - 393216;
        int n = j >> 8, k = j & 255;
        Wot[j] = __float2half(Wo[(size_t)k * 64 + n]);
    } else if (idx < 410624) {
        int n = idx - 409600;
        int sel, c; unpermute_col(n, sel, c);
        const float* b = (sel == 0) ? bq1 : (sel == 1) ? bk1 : (sel == 2) ? bv1 : bs1;
        bc1[n] = b[c];
    } else if (idx < 411648) {
        int n = idx - 410624;
        int sel, c; unpermute_col(n, sel, c);
        const float* b = (sel == 0) ? bq2 : (sel == 1) ? bk2 : (sel == 2) ? bv2 : bs2;
        bc2[n] = b[c];
    }
}

// ---------------- MFMA GEMM: C[M x Nc] = A[M x K] @ Wt^T + bias (f16 out) ----------------
// R13: 1-D grid + XCD-grouping swizzle. Dispatch->XCD is round-robin (bid%8);
// remap so the 8 col-blocks sharing one A row-panel land on ONE XCD and run
// near-concurrently -> A panel (64KB) fetched once into that XCD's 4MB L2
// instead of 8x from L3/HBM (A re-read traffic 205MB -> 26MB for the K=256 gemm).
#define BM 128
#define BN 128
#define BK 64
#define TROWB 272   // f16 out-tile row stride (bytes)

__global__ __launch_bounds__(256) void gemm_mfma(
    const __half* __restrict__ A, const __half* __restrict__ Wt,
    const float* __restrict__ bias, __half* __restrict__ C,
    unsigned char* __restrict__ kv8,
    int M, int K, int Nc)
{
    __shared__ char smem[BM * TROWB];
    _Float16* As = (_Float16*)smem;
    _Float16* Bs = (_Float16*)(smem + 16384);

    int tid = threadIdx.x;
    int lane = tid & 63, w = tid >> 6;
    int wm = w >> 1, wn = w & 1;
    int quad = lane >> 4, l16 = lane & 15;
    // XCD swizzle: nwg = nbx*8 (exact multiple of 8 XCDs)
    int nbx = (int)gridDim.x >> 3;
    int wkr = ((int)blockIdx.x & 7) * nbx + ((int)blockIdx.x >> 3);
    int row0 = (wkr >> 3) * BM;
    int col0 = (wkr & 7) * BN;

    f32x4 acc[4][4];
#pragma unroll
    for (int i = 0; i < 4; i++)
#pragma unroll
        for (int j = 0; j < 4; j++) acc[i][j] = (f32x4){0.f, 0.f, 0.f, 0.f};

    int srow = lane >> 3;
    int schunk = lane & 7;

    for (int k0 = 0; k0 < K; k0 += BK) {
#pragma unroll
        for (int t = 0; t < 4; t++) {
            int r = w * 32 + t * 8 + srow;
            int gr = row0 + r; if (gr > M - 1) gr = M - 1;
            int gchunk = schunk ^ (r & 7);
            async_copy16(&A[(size_t)gr * K + k0 + gchunk * 8], &As[(w * 32 + t * 8) * 64]);
        }
#pragma unroll
        for (int t = 0; t < 4; t++) {
            int r = w * 32 + t * 8 + srow;
            int gc = col0 + r; if (gc > Nc - 1) gc = Nc - 1;
            int gchunk = schunk ^ (r & 7);
            async_copy16(&Wt[(size_t)gc * K + k0 + gchunk * 8], &Bs[(w * 32 + t * 8) * 64]);
        }
        __syncthreads();

#pragma unroll
        for (int ks = 0; ks < 2; ks++) {
            half8 af[4], bf[4];
#pragma unroll
            for (int i = 0; i < 4; i++) {
                int ra = wm * 64 + i * 16 + l16;
                af[i] = *(half8*)&As[ra * 64 + (((ks * 4 + quad) ^ (ra & 7)) * 8)];
                int rb = wn * 64 + i * 16 + l16;
                bf[i] = *(half8*)&Bs[rb * 64 + (((ks * 4 + quad) ^ (rb & 7)) * 8)];
            }
#pragma unroll
            for (int i = 0; i < 4; i++)
#pragma unroll
                for (int j = 0; j < 4; j++)
                    acc[i][j] = __builtin_amdgcn_mfma_f32_16x16x32_f16(af[i], bf[j], acc[i][j], 0, 0, 0);
        }
        __syncthreads();
    }

#pragma unroll
    for (int j = 0; j < 4; j++) {
        int tcol = wn * 64 + j * 16 + l16;
        float bb = (col0 + tcol < Nc) ? bias[col0 + tcol] : 0.f;
#pragma unroll
        for (int i = 0; i < 4; i++) {
#pragma unroll
            for (int r = 0; r < 4; r++) {
                int trow = wm * 64 + i * 16 + quad * 4 + r;
                ((__half*)(smem + trow * TROWB))[tcol] = __float2half(acc[i][j][r] + bb);
            }
        }
    }
    __syncthreads();
    bool iskv = (col0 >= 256) && (col0 < 768);
    int crow = tid >> 4, cchunk = tid & 15;
    for (int p = 0; p < 8; p++) {
        int trow = p * 16 + crow;
        int grow = row0 + trow;
        if (grow >= M) continue;
        uint4 val = *(uint4*)(smem + trow * TROWB + cchunk * 16);
        if (iskv) {
            float4 lo = h4_to_f4(make_uint2(val.x, val.y));
            float4 hi = h4_to_f4(make_uint2(val.z, val.w));
            uint2 o8;
            o8.x = f4_to_fp8x4(lo.x, lo.y, lo.z, lo.w);
            o8.y = f4_to_fp8x4(hi.x, hi.y, hi.z, hi.w);
            *(uint2*)&kv8[(size_t)grow * 512 + (col0 - 256) + cchunk * 8] = o8;
        } else {
            *(uint4*)&C[(size_t)grow * Nc + col0 + cchunk * 8] = val;
        }
    }
}

// ---------------- output GEMM: D[M x 64] = A[M x 256] @ Wot^T + bo (fp32 out) ----------
__global__ __launch_bounds__(256) void gemm_out_k(
    const __half* __restrict__ A, const __half* __restrict__ Wot,
    const float* __restrict__ bias, float* __restrict__ D, int M)
{
    __shared__ _Float16 As[128 * 64];   // 16 KB
    __shared__ _Float16 Bs[64 * 64];    // 8 KB
    int tid = threadIdx.x;
    int lane = tid & 63, w = tid >> 6;
    int quad = lane >> 4, l16 = lane & 15;
    int row0 = blockIdx.x * 128;
    const int K = 256;

    f32x4 acc[2][4];
#pragma unroll
    for (int i = 0; i < 2; i++)
#pragma unroll
        for (int j = 0; j < 4; j++) acc[i][j] = (f32x4){0.f, 0.f, 0.f, 0.f};

    int srow = lane >> 3;
    int schunk = lane & 7;

    for (int k0 = 0; k0 < K; k0 += BK) {
#pragma unroll
        for (int t = 0; t < 4; t++) {
            int r = w * 32 + t * 8 + srow;
            int gr = row0 + r; if (gr > M - 1) gr = M - 1;
            int gchunk = schunk ^ (r & 7);
            async_copy16(&A[(size_t)gr * K + k0 + gchunk * 8], &As[(w * 32 + t * 8) * 64]);
        }
#pragma unroll
        for (int t = 0; t < 2; t++) {
            int r = w * 16 + t * 8 + srow;     // 64 weight rows
            int gchunk = schunk ^ (r & 7);
            async_copy16(&Wot[(size_t)r * K + k0 + gchunk * 8], &Bs[(w * 16 + t * 8) * 64]);
        }
        __syncthreads();

#pragma unroll
        for (int ks = 0; ks < 2; ks++) {
            half8 af[2], bf[4];
#pragma unroll
            for (int i = 0; i < 2; i++) {
                int ra = w * 32 + i * 16 + l16;
                af[i] = *(half8*)&As[ra * 64 + (((ks * 4 + quad) ^ (ra & 7)) * 8)];
            }
#pragma unroll
            for (int j = 0; j < 4; j++) {
                int rb = j * 16 + l16;
                bf[j] = *(half8*)&Bs[rb * 64 + (((ks * 4 + quad) ^ (rb & 7)) * 8)];
            }
#pragma unroll
            for (int i = 0; i < 2; i++)
#pragma unroll
                for (int j = 0; j < 4; j++)
                    acc[i][j] = __builtin_amdgcn_mfma_f32_16x16x32_f16(af[i], bf[j], acc[i][j], 0, 0, 0);
        }
        __syncthreads();
    }

#pragma unroll
    for (int i = 0; i < 2; i++) {
#pragma unroll
        for (int j = 0; j < 4; j++) {
            int gcol = j * 16 + l16;
            float bb = bias[gcol];
#pragma unroll
            for (int r = 0; r < 4; r++) {
                int grow = row0 + w * 32 + i * 16 + quad * 4 + r;
                if (grow < M) D[(size_t)grow * 64 + gcol] = acc[i][j][r] + bb;
            }
        }
    }
}

// ---------------- edge bucketing ----------------
__global__ __launch_bounds__(1024) void scan_k(const int* __restrict__ counts,
                                               int* __restrict__ offs, int n)
{
    __shared__ int wsum[16];
    __shared__ int wpre[16];
    int tid = threadIdx.x, lane = tid & 63, wid = tid >> 6;
    int per = (n + 1023) / 1024;
    int start = tid * per, end = min(start + per, n);
    int sum = 0;
    for (int i = start; i < end; i++) sum += counts[i];
    int v = sum;
#pragma unroll
    for (int d = 1; d < 64; d <<= 1) {
        int t = __shfl_up(v, (unsigned)d, 64);
        if (lane >= d) v += t;
    }
    if (lane == 63) wsum[wid] = v;
    __syncthreads();
    if (tid == 0) {
        int acc = 0;
        for (int i = 0; i < 16; i++) { wpre[i] = acc; acc += wsum[i]; }
    }
    __syncthreads();
    int pre = wpre[wid] + v - sum;
    for (int i = start; i < end; i++) { offs[i] = pre; pre += counts[i]; }
    if (end == n && start <= n) offs[n] = pre;
}

// atomic-free: position = segment offset + precomputed rank
// R13: also writes 8 pad entries (src=0, attr=0) past the end so attn can
// load full batches unconditionally (pad scores forced to -inf in attn).
__global__ void scatter_k(const int* __restrict__ src, const int* __restrict__ dst,
                          const float* __restrict__ attr, const int* __restrict__ offs,
                          const int* __restrict__ rank, int2* __restrict__ edat, int E)
{
    int e = blockIdx.x * 256 + threadIdx.x;
    if (e < 8) edat[E + e] = make_int2(0, 0);
    if (e < E) {
        int p = offs[dst[e]] + rank[e];
        edat[p] = make_int2(src[e], __float_as_int(attr[e]));
    }
}

// ---------------- attention: one wave per dst node, batched online softmax ----
// R4-MEASURED VERSION, EXACT SOURCE (108us, VGPR=64, SGPR=80, occ 35%).
// DO NOT REPHRASE THIS LOOP. R7 measured: rewriting the ping-pong with a
// runtime curB bool selecting buffers cost +8 VGPR (64->72) -> 7 waves/SIMD
// -> 117us. The statically-unrolled two-phase body below is load-bearing.
// HARD CONSTRAINT (R5/R6/R7): VGPR <= 64 — kernel is TLP-limited.
__global__ __launch_bounds__(256) void attn_k(
    const uint2* __restrict__ q2, const uint2* __restrict__ kv8u2,
    const float* __restrict__ We,
    __half* __restrict__ hwork, const int2* __restrict__ edat,
    const int* __restrict__ offs,
    double* __restrict__ stats, int n, int nGroups)
{
    int lane = threadIdx.x & 63;
    int wid = threadIdx.x >> 6;
    float4 we = ((const float4*)We)[lane];
    float tsum = 0.f, tsq = 0.f;

    for (int g = blockIdx.x; g < nGroups; g += gridDim.x) {
        int node = g * 4 + wid;
        if (node >= n) continue;
        float4 qv = h4_to_f4(q2[(size_t)node * 256 + lane]);
        float qwe = qv.x * we.x + qv.y * we.y + qv.z * we.z + qv.w * we.w;
        qwe += __shfl_xor(qwe, 1);
        qwe += __shfl_xor(qwe, 2);
        qwe += __shfl_xor(qwe, 4);

        float4 accv = make_float4(0.f, 0.f, 0.f, 0.f);
        float sat = 0.f;
        float m = -INFINITY, l = 0.f;
        int i0 = __builtin_amdgcn_readfirstlane(offs[node]);
        int i1 = __builtin_amdgcn_readfirstlane(offs[node + 1]);

        int abA[8], srA[8], abB[8], srB[8];   // SGPR: attr bits / src index
        uint2 kvA[8], kvB[8];

        auto LOADB = [&](int base, int* ab_, int* sr_, uint2* kv_) {
#pragma unroll
            for (int u = 0; u < 8; u++) {
                int2 ed = edat[base + u];                     // uniform addr
                sr_[u] = __builtin_amdgcn_readfirstlane(ed.x);
                ab_[u] = __builtin_amdgcn_readfirstlane(ed.y);
            }
#pragma unroll
            for (int u = 0; u < 8; u++)
                kv_[u] = (kv8u2 + (size_t)(unsigned)sr_[u] * 64)[lane];
        };

        auto COMPUTE = [&](const int* ab_, const uint2* kv_, int cnt) {
            float pv[8];
#pragma unroll
            for (int u = 0; u < 8; u++) {
                float4 kvf = fp8x4_to_f4(kv_[u].x);
                float p = qv.x * kvf.x + qv.y * kvf.y + qv.z * kvf.z + qv.w * kvf.w;
                p += __shfl_xor(p, 1);
                p += __shfl_xor(p, 2);
                p += __shfl_xor(p, 4);
                p = fmaf(__int_as_float(ab_[u]), qwe, p) * 0.17677669529663687f;
                pv[u] = (u < cnt) ? p : -INFINITY;            // folds away for cnt=8
            }
            float m01 = fmaxf(pv[0], pv[1]), m23 = fmaxf(pv[2], pv[3]);
            float m45 = fmaxf(pv[4], pv[5]), m67 = fmaxf(pv[6], pv[7]);
            float pmax = fmaxf(fmaxf(m01, m23), fmaxf(m45, m67));
            float mn = fmaxf(m, pmax);
            float corr = __expf(m - mn);
            l *= corr;
            sat *= corr;
            accv.x *= corr; accv.y *= corr; accv.z *= corr; accv.w *= corr;
#pragma unroll
            for (int u = 0; u < 8; u++) {
                float wgt = __expf(pv[u] - mn);               // pad: exp(-inf)=0
                l += wgt;
                sat = fmaf(wgt, __int_as_float(ab_[u]), sat);
                float4 vv = fp8x4_to_f4(kv_[u].y);
                accv.x = fmaf(wgt, vv.x, accv.x);
                accv.y = fmaf(wgt, vv.y, accv.y);
                accv.z = fmaf(wgt, vv.z, accv.z);
                accv.w = fmaf(wgt, vv.w, accv.w);
            }
            m = mn;
        };

        if (i0 < i1) {
            int i = i0;
            LOADB(i, abA, srA, kvA);
            while (true) {
                if (i + 8 >= i1) { COMPUTE(abA, kvA, i1 - i); break; }
                LOADB(i + 8, abB, srB, kvB);
                COMPUTE(abA, kvA, 8);
                i += 8;
                if (i + 8 >= i1) { COMPUTE(abB, kvB, i1 - i); break; }
                LOADB(i + 8, abA, srA, kvA);
                COMPUTE(abB, kvB, 8);
                i += 8;
            }
        }

        float inv = (l > 0.f) ? 1.f / l : 0.f;
        float4 sk = h4_to_f4(q2[(size_t)node * 256 + 192 + lane]);
        float sw = sat * inv;
        float4 o;
        o.x = fmaf(accv.x, inv, fmaf(sw, we.x, sk.x));
        o.y = fmaf(accv.y, inv, fmaf(sw, we.y, sk.y));
        o.z = fmaf(accv.z, inv, fmaf(sw, we.z, sk.z));
        o.w = fmaf(accv.w, inv, fmaf(sw, we.w, sk.w));
        store4(hwork + (size_t)node * 256 + lane * 4, o);
        tsum += o.x + o.y + o.z + o.w;
        tsq += o.x * o.x + o.y * o.y + o.z * o.z + o.w * o.w;
    }

#pragma unroll
    for (int d = 1; d < 64; d <<= 1) {
        tsum += __shfl_xor(tsum, d);
        tsq += __shfl_xor(tsq, d);
    }
    __shared__ float red[8];
    if (lane == 0) { red[wid] = tsum; red[4 + wid] = tsq; }
    __syncthreads();
    if (threadIdx.x == 0) {
        double s = (double)red[0] + (double)red[1] + (double)red[2] + (double)red[3];
        double sq = (double)red[4] + (double)red[5] + (double)red[6] + (double)red[7];
        atomicAdd(&stats[0], s);
        atomicAdd(&stats[1], sq);
    }
}

// ---------------- LayerNorm apply (f16 in, f16 out; 4 elems/thread) ----------------
__global__ __launch_bounds__(256) void ln_apply(
    const uint2* __restrict__ in, __half* __restrict__ out,
    const float4* __restrict__ w4, const float4* __restrict__ b4,
    const double* __restrict__ stats, double cnt, int total4)
{
    int base = (blockIdx.x * 256 + threadIdx.x) * 4;
    if (base >= total4) return;
    double mu = stats[0] / cnt;
    double var = stats[1] / cnt - mu * mu;
    if (var < 0.0) var = 0.0;
    float mean = (float)mu;
    float inv = (float)(1.0 / (sqrt(var) + (double)EPSLN));
#pragma unroll
    for (int u = 0; u < 4; u++) {
        int i = base + u;
        if (i >= total4) return;
        int c = i & 63;
        float4 xv = h4_to_f4(in[i]);
        float4 w = w4[c], b = b4[c];
        float4 o;
        o.x = fmaf((xv.x - mean) * inv, w.x, b.x);
        o.y = fmaf((xv.y - mean) * inv, w.y, b.y);
        o.z = fmaf((xv.z - mean) * inv, w.z, b.z);
        o.w = fmaf((xv.w - mean) * inv, w.w, b.w);
        o.x = o.x > 0.f ? o.x : expm1f(o.x);
        o.y = o.y > 0.f ? o.y : expm1f(o.y);
        o.z = o.z > 0.f ? o.z : expm1f(o.z);
        o.w = o.w > 0.f ? o.w : expm1f(o.w);
        store4(out + (size_t)i * 4, o);
    }
}

// ---------------- driver ----------------
extern "C" void kernel_launch(void* const* d_in, const int* in_sizes, int n_in,
                              void* d_out, int out_size, void* d_ws, size_t ws_size,
                              hipStream_t stream)
{
    const float* x      = (const float*)d_in[0];
    const int*   ei     = (const int*)d_in[1];
    const float* eattr  = (const float*)d_in[2];
    const float* Wq1 = (const float*)d_in[3];  const float* bq1 = (const float*)d_in[4];
    const float* Wk1 = (const float*)d_in[5];  const float* bk1 = (const float*)d_in[6];
    const float* Wv1 = (const float*)d_in[7];  const float* bv1 = (const float*)d_in[8];
    const float* We1 = (const float*)d_in[9];
    const float* Ws1 = (const float*)d_in[10]; const float* bs1 = (const float*)d_in[11];
    const float* lnw1 = (const float*)d_in[12]; const float* lnb1 = (const float*)d_in[13];
    const float* Wq2 = (const float*)d_in[14]; const float* bq2 = (const float*)d_in[15];
    const float* Wk2 = (const float*)d_in[16]; const float* bk2 = (const float*)d_in[17];
    const float* Wv2 = (const float*)d_in[18]; const float* bv2 = (const float*)d_in[19];
    const float* We2 = (const float*)d_in[20];
    const float* Ws2 = (const float*)d_in[21]; const float* bs2 = (const float*)d_in[22];
    const float* lnw2 = (const float*)d_in[23]; const float* lnb2 = (const float*)d_in[24];
    const float* Wo  = (const float*)d_in[25]; const float* bo  = (const float*)d_in[26];

    const int N = in_sizes[0] / IN_DIM;
    const int E = in_sizes[2];
    const int* esrc = ei;
    const int* edst = ei + E;

    char* ws = (char*)d_ws;
    size_t off = 0;
    auto alloc = [&](size_t bytes) -> char* {
        char* p = ws + off;
        off += (bytes + 255) / 256 * 256;
        return p;
    };
    int*    counts = (int*)alloc((size_t)N * 4);
    double* stats  = (double*)alloc(64);
    size_t zbytes = off;
    int*    rank   = (int*)alloc((size_t)E * 4);
    int*    offs   = (int*)alloc((size_t)(N + 1) * 4);
    int2*   edat   = (int2*)alloc((size_t)(E + 8) * 8);
    __half* xh     = (__half*)alloc((size_t)N * IN_DIM * 2);
    __half* qkvs   = (__half*)alloc((size_t)N * 1024 * 2);
    unsigned char* kv8 = (unsigned char*)alloc((size_t)N * 512);
    __half* hwork  = (__half*)alloc((size_t)N * HD * 2);
    __half* hio    = (__half*)alloc((size_t)N * HD * 2);
    __half* Wc1    = (__half*)alloc((size_t)1024 * IN_DIM * 2);
    __half* Wc2    = (__half*)alloc((size_t)1024 * HD * 2);
    __half* Wot    = (__half*)alloc((size_t)64 * HD * 2);
    float*  bc1    = (float*)alloc(1024 * 4);
    float*  bc2    = (float*)alloc(1024 * 4);

    hipMemsetAsync(d_ws, 0, zbytes, stream);

    int total4x = N * (IN_DIM / 4);
    int prepWork = total4x > E ? total4x : E;
    if (prepWork < 411648) prepWork = 411648;
    prep_k<<<(prepWork + 255) / 256, 256, 0, stream>>>(
        (const float4*)x, xh, total4x, edst, counts, rank, E,
        Wq1, Wk1, Wv1, Ws1, Wq2, Wk2, Wv2, Ws2, Wo,
        bq1, bk1, bv1, bs1, bq2, bk2, bv2, bs2,
        Wc1, Wc2, Wot, bc1, bc2);

    scan_k<<<1, 1024, 0, stream>>>(counts, offs, N);
    scatter_k<<<(E + 255) / 256, 256, 0, stream>>>(esrc, edst, eattr, offs, rank,
                                                   edat, E);

    int nbx = (N + BM - 1) / BM;
    dim3 gqkvs(nbx * 8);                              // 1-D grid for XCD swizzle
    int nGroups = (N + 3) / 4;
    int gaBlocks = nGroups < 2048 ? nGroups : 2048;   // persistent blocks (proven R8 config)
    int total4 = N * (HD / 4);
    dim3 gl((total4 / 4 + 255) / 256);
    dim3 gout((N + 127) / 128);

    // ---- layer 1 ----
    gemm_mfma<<<gqkvs, 256, 0, stream>>>(xh, Wc1, bc1, qkvs, kv8, N, IN_DIM, 1024);
    attn_k<<<gaBlocks, 256, 0, stream>>>((const uint2*)qkvs, (const uint2*)kv8, We1,
                                         hwork, edat, offs, stats, N, nGroups);
    ln_apply<<<gl, 256, 0, stream>>>((const uint2*)hwork, hio,
                                     (const float4*)lnw1, (const float4*)lnb1,
                                     stats, (double)N * HD, total4);

    // ---- layer 2 ----
    gemm_mfma<<<gqkvs, 256, 0, stream>>>(hio, Wc2, bc2, qkvs, kv8, N, HD, 1024);
    attn_k<<<gaBlocks, 256, 0, stream>>>((const uint2*)qkvs, (const uint2*)kv8, We2,
                                         hwork, edat, offs, stats + 2, N, nGroups);
    ln_apply<<<gl, 256, 0, stream>>>((const uint2*)hwork, hio,
                                     (const float4*)lnw2, (const float4*)lnb2,
                                     stats + 2, (double)N * HD, total4);

    // ---- output projection (fp32 out, dedicated 128x64 kernel) ----
    gemm_out_k<<<gout, 256, 0, stream>>>(hio, Wot, bo, (float*)d_out, N);
}

// Round 11
// 573.935 us; speedup vs baseline: 2.9283x; 1.0032x over previous
//
#include <hip/hip_runtime.h>
#include <hip/hip_fp16.h>
#include <math.h>

#define IN_DIM 128
#define HD 256
#define EPSLN 1e-5f

typedef _Float16 half8 __attribute__((ext_vector_type(8)));
typedef float f32x4 __attribute__((ext_vector_type(4)));
typedef float f32x2 __attribute__((ext_vector_type(2)));

// ---------------- helpers ----------------
__device__ inline void store4(float* p, float4 o) { *(float4*)p = o; }
__device__ inline void store4(__half* p, float4 o) {
    union { uint2 u; __half2 h[2]; } s;
    s.h[0] = __floats2half2_rn(o.x, o.y);
    s.h[1] = __floats2half2_rn(o.z, o.w);
    *(uint2*)p = s.u;
}
__device__ inline float4 h4_to_f4(uint2 u) {
    union { unsigned int w; __half2 h; } a, b;
    a.w = u.x; b.w = u.y;
    float2 lo = __half22float2(a.h), hi = __half22float2(b.h);
    return make_float4(lo.x, lo.y, hi.x, hi.y);
}
// 4 floats -> 4 packed fp8 e4m3 (OCP, gfx950 HW cvt)
__device__ inline unsigned int f4_to_fp8x4(float a, float b, float c, float d) {
    int v = 0;
    v = __builtin_amdgcn_cvt_pk_fp8_f32(a, b, v, false);
    v = __builtin_amdgcn_cvt_pk_fp8_f32(c, d, v, true);
    return (unsigned int)v;
}
__device__ inline float4 fp8x4_to_f4(unsigned int u) {
    f32x2 lo = __builtin_amdgcn_cvt_pk_f32_fp8((int)u, false);
    f32x2 hi = __builtin_amdgcn_cvt_pk_f32_fp8((int)u, true);
    return make_float4(lo.x, lo.y, hi.x, hi.y);
}

__device__ inline void async_copy16(const __half* g, _Float16* l) {
    __builtin_amdgcn_global_load_lds(
        (const __attribute__((address_space(1))) void*)g,
        (__attribute__((address_space(3))) void*)l,
        16, 0, 0);
}

// Packed output column mapping: q[0:256) | kv-interleaved[256:768) | skip[768:1024)
__device__ inline void unpermute_col(int n, int& sel, int& c) {
    if (n < 256) { sel = 0; c = n; }
    else if (n < 768) {
        int j = n - 256, chunk = j >> 3, w = j & 7;
        if (w < 4) { sel = 1; c = chunk * 4 + w; }
        else       { sel = 2; c = chunk * 4 + w - 4; }
    } else { sel = 3; c = n - 768; }
}

// ---------------- fused prep: pack x, pack weights/biases, count degrees + ranks ----
__global__ void prep_k(
    const float4* __restrict__ x, __half* __restrict__ xh, int total4,
    const int* __restrict__ dst, int* __restrict__ counts, int* __restrict__ rank, int E,
    const float* __restrict__ Wq1, const float* __restrict__ Wk1,
    const float* __restrict__ Wv1, const float* __restrict__ Ws1,
    const float* __restrict__ Wq2, const float* __restrict__ Wk2,
    const float* __restrict__ Wv2, const float* __restrict__ Ws2,
    const float* __restrict__ Wo,
    const float* __restrict__ bq1, const float* __restrict__ bk1,
    const float* __restrict__ bv1, const float* __restrict__ bs1,
    const float* __restrict__ bq2, const float* __restrict__ bk2,
    const float* __restrict__ bv2, const float* __restrict__ bs2,
    __half* __restrict__ Wc1, __half* __restrict__ Wc2, __half* __restrict__ Wot,
    float* __restrict__ bc1, float* __restrict__ bc2)
{
    int idx = blockIdx.x * 256 + threadIdx.x;
    if (idx < total4) store4(xh + (size_t)idx * 4, x[idx]);
    if (idx < E) rank[idx] = atomicAdd(&counts[dst[idx]], 1);   // rank within dst bucket
    if (idx < 131072) {
        int n = idx >> 7, k = idx & 127;
        int sel, c; unpermute_col(n, sel, c);
        const float* W = (sel == 0) ? Wq1 : (sel == 1) ? Wk1 : (sel == 2) ? Wv1 : Ws1;
        Wc1[idx] = __float2half(W[(size_t)k * 256 + c]);
    } else if (idx < 393216) {
        int j = idx - 131072;
        int n = j >> 8, k = j & 255;
        int sel, c; unpermute_col(n, sel, c);
        const float* W = (sel == 0) ? Wq2 : (sel == 1) ? Wk2 : (sel == 2) ? Wv2 : Ws2;
        Wc2[j] = __float2half(W[(size_t)k * 256 + c]);
    } else if (idx < 409600) {
        int j = idx - 393216;
        int n = j >> 8, k = j & 255;
        Wot[j] = __float2half(Wo[(size_t)k * 64 + n]);
    } else if (idx < 410624) {
        int n = idx - 409600;
        int sel, c; unpermute_col(n, sel, c);
        const float* b = (sel == 0) ? bq1 : (sel == 1) ? bk1 : (sel == 2) ? bv1 : bs1;
        bc1[n] = b[c];
    } else if (idx < 411648) {
        int n = idx - 410624;
        int sel, c; unpermute_col(n, sel, c);
        const float* b = (sel == 0) ? bq2 : (sel == 1) ? bk2 : (sel == 2) ? bv2 : bs2;
        bc2[n] = b[c];
    }
}

// ---------------- MFMA GEMM: C[M x Nc] = A[M x K] @ Wt^T + bias (f16 out) ----------------
// R13: 1-D grid + XCD-grouping swizzle (measured R4: ~44us win across both gemms).
// R17/R18: BK=32 single-barrier double-buffer pipeline. K is tiny (128/256 ->
// 2-4 BK=64 steps), so the old stage->barrier->compute->barrier structure
// exposed the full staging latency every step. Now stage t+1 issues BEFORE
// compute t; the step-end __syncthreads drain lands after compute covered the
// latency. LDS layout (34,816B region): As0@0, Bs0@8K, As1@16K, Bs1@24K.
// Buffer bases computed per-use (pointer ARRAYS into LDS fail to compile on
// gfx950: "unsupported expression in static initializer" — R10 lesson).
// 4-chunk XOR swizzle c ^ ((r^(r>>2))&3): 2-way-max ds_read_b128 conflicts (free).
#define BM 128
#define BN 128
#define TROWB 272   // f16 out-tile row stride (bytes)

__global__ __launch_bounds__(256) void gemm_mfma(
    const __half* __restrict__ A, const __half* __restrict__ Wt,
    const float* __restrict__ bias, __half* __restrict__ C,
    unsigned char* __restrict__ kv8,
    int M, int K, int Nc)
{
    __shared__ char smem[BM * TROWB];          // 34,816 B; dbuf overlaid below

    int tid = threadIdx.x;
    int lane = tid & 63, w = tid >> 6;
    int wm = w >> 1, wn = w & 1;
    int quad = lane >> 4, l16 = lane & 15;
    // XCD swizzle: nwg = nbx*8 (exact multiple of 8 XCDs)
    int nbx = (int)gridDim.x >> 3;
    int wkr = ((int)blockIdx.x & 7) * nbx + ((int)blockIdx.x >> 3);
    int row0 = (wkr >> 3) * BM;
    int col0 = (wkr & 7) * BN;

    f32x4 acc[4][4];
#pragma unroll
    for (int i = 0; i < 4; i++)
#pragma unroll
        for (int j = 0; j < 4; j++) acc[i][j] = (f32x4){0.f, 0.f, 0.f, 0.f};

    int srow = lane >> 2;      // 0..15 (16 rows per wave-instruction at BK=32)
    int schunk = lane & 3;     // 4 chunks of 8 f16 per 64B row

    int nt = K >> 5;           // K/32 steps

    // STAGE(step, buf): issue A+B tile loads for k0 = step*32 into buffer buf
    auto STAGE = [&](int step, int buf) {
        int k0 = step << 5;
        _Float16* Asb = (_Float16*)(smem + buf * 16384);
        _Float16* Bsb = (_Float16*)(smem + 8192 + buf * 16384);
#pragma unroll
        for (int t = 0; t < 2; t++) {
            int r = w * 32 + t * 16 + srow;
            int gr = row0 + r; if (gr > M - 1) gr = M - 1;
            int gchunk = schunk ^ ((r ^ (r >> 2)) & 3);
            async_copy16(&A[(size_t)gr * K + k0 + gchunk * 8], &Asb[(w * 32 + t * 16) * 32]);
        }
#pragma unroll
        for (int t = 0; t < 2; t++) {
            int r = w * 32 + t * 16 + srow;
            int gc = col0 + r; if (gc > Nc - 1) gc = Nc - 1;
            int gchunk = schunk ^ ((r ^ (r >> 2)) & 3);
            async_copy16(&Wt[(size_t)gc * K + k0 + gchunk * 8], &Bsb[(w * 32 + t * 16) * 32]);
        }
    };

    STAGE(0, 0);
    __syncthreads();

    for (int t = 0; t < nt; ++t) {
        if (t + 1 < nt) STAGE(t + 1, (t + 1) & 1);
        _Float16* Asb = (_Float16*)(smem + (t & 1) * 16384);
        _Float16* Bsb = (_Float16*)(smem + 8192 + (t & 1) * 16384);
        half8 af[4], bf[4];
#pragma unroll
        for (int i = 0; i < 4; i++) {
            int ra = wm * 64 + i * 16 + l16;
            af[i] = *(half8*)&Asb[ra * 32 + ((quad ^ ((ra ^ (ra >> 2)) & 3)) * 8)];
            int rb = wn * 64 + i * 16 + l16;
            bf[i] = *(half8*)&Bsb[rb * 32 + ((quad ^ ((rb ^ (rb >> 2)) & 3)) * 8)];
        }
#pragma unroll
        for (int i = 0; i < 4; i++)
#pragma unroll
            for (int j = 0; j < 4; j++)
                acc[i][j] = __builtin_amdgcn_mfma_f32_16x16x32_f16(af[i], bf[j], acc[i][j], 0, 0, 0);
        __syncthreads();
    }

#pragma unroll
    for (int j = 0; j < 4; j++) {
        int tcol = wn * 64 + j * 16 + l16;
        float bb = (col0 + tcol < Nc) ? bias[col0 + tcol] : 0.f;
#pragma unroll
        for (int i = 0; i < 4; i++) {
#pragma unroll
            for (int r = 0; r < 4; r++) {
                int trow = wm * 64 + i * 16 + quad * 4 + r;
                ((__half*)(smem + trow * TROWB))[tcol] = __float2half(acc[i][j][r] + bb);
            }
        }
    }
    __syncthreads();
    bool iskv = (col0 >= 256) && (col0 < 768);
    int crow = tid >> 4, cchunk = tid & 15;
    for (int p = 0; p < 8; p++) {
        int trow = p * 16 + crow;
        int grow = row0 + trow;
        if (grow >= M) continue;
        uint4 val = *(uint4*)(smem + trow * TROWB + cchunk * 16);
        if (iskv) {
            float4 lo = h4_to_f4(make_uint2(val.x, val.y));
            float4 hi = h4_to_f4(make_uint2(val.z, val.w));
            uint2 o8;
            o8.x = f4_to_fp8x4(lo.x, lo.y, lo.z, lo.w);
            o8.y = f4_to_fp8x4(hi.x, hi.y, hi.z, hi.w);
            *(uint2*)&kv8[(size_t)grow * 512 + (col0 - 256) + cchunk * 8] = o8;
        } else {
            *(uint4*)&C[(size_t)grow * Nc + col0 + cchunk * 8] = val;
        }
    }
}

// ---------------- output GEMM: D[M x 64] = A[M x 256] @ Wot^T + bo (fp32 out) ----------
// R17/R18: same BK=32 single-barrier double-buffer as gemm_mfma. LDS 24KB.
// Layout (halfs): As0@0 (4096), As1@4096, Bs0@8192 (2048), Bs1@10240.
__global__ __launch_bounds__(256) void gemm_out_k(
    const __half* __restrict__ A, const __half* __restrict__ Wot,
    const float* __restrict__ bias, float* __restrict__ D, int M)
{
    __shared__ _Float16 smem[12288];   // 24 KB
    int tid = threadIdx.x;
    int lane = tid & 63, w = tid >> 6;
    int quad = lane >> 4, l16 = lane & 15;
    int row0 = blockIdx.x * 128;
    const int K = 256;

    f32x4 acc[2][4];
#pragma unroll
    for (int i = 0; i < 2; i++)
#pragma unroll
        for (int j = 0; j < 4; j++) acc[i][j] = (f32x4){0.f, 0.f, 0.f, 0.f};

    int srow = lane >> 2;
    int schunk = lane & 3;
    const int nt = 8;   // 256/32

    auto STAGE = [&](int step, int buf) {
        int k0 = step << 5;
        _Float16* Asb = smem + buf * 4096;
        _Float16* Bsb = smem + 8192 + buf * 2048;
#pragma unroll
        for (int t = 0; t < 2; t++) {
            int r = w * 32 + t * 16 + srow;
            int gr = row0 + r; if (gr > M - 1) gr = M - 1;
            int gchunk = schunk ^ ((r ^ (r >> 2)) & 3);
            async_copy16(&A[(size_t)gr * K + k0 + gchunk * 8], &Asb[(w * 32 + t * 16) * 32]);
        }
        {
            int r = w * 16 + srow;       // 64 weight rows, one wave-inst per wave
            int gchunk = schunk ^ ((r ^ (r >> 2)) & 3);
            async_copy16(&Wot[(size_t)r * K + k0 + gchunk * 8], &Bsb[(w * 16) * 32]);
        }
    };

    STAGE(0, 0);
    __syncthreads();

    for (int t = 0; t < nt; ++t) {
        if (t + 1 < nt) STAGE(t + 1, (t + 1) & 1);
        _Float16* Asb = smem + (t & 1) * 4096;
        _Float16* Bsb = smem + 8192 + (t & 1) * 2048;
        half8 af[2], bf[4];
#pragma unroll
        for (int i = 0; i < 2; i++) {
            int ra = w * 32 + i * 16 + l16;
            af[i] = *(half8*)&Asb[ra * 32 + ((quad ^ ((ra ^ (ra >> 2)) & 3)) * 8)];
        }
#pragma unroll
        for (int j = 0; j < 4; j++) {
            int rb = j * 16 + l16;
            bf[j] = *(half8*)&Bsb[rb * 32 + ((quad ^ ((rb ^ (rb >> 2)) & 3)) * 8)];
        }
#pragma unroll
        for (int i = 0; i < 2; i++)
#pragma unroll
            for (int j = 0; j < 4; j++)
                acc[i][j] = __builtin_amdgcn_mfma_f32_16x16x32_f16(af[i], bf[j], acc[i][j], 0, 0, 0);
        __syncthreads();
    }

#pragma unroll
    for (int i = 0; i < 2; i++) {
#pragma unroll
        for (int j = 0; j < 4; j++) {
            int gcol = j * 16 + l16;
            float bb = bias[gcol];
#pragma unroll
            for (int r = 0; r < 4; r++) {
                int grow = row0 + w * 32 + i * 16 + quad * 4 + r;
                if (grow < M) D[(size_t)grow * 64 + gcol] = acc[i][j][r] + bb;
            }
        }
    }
}

// ---------------- edge bucketing ----------------
__global__ __launch_bounds__(1024) void scan_k(const int* __restrict__ counts,
                                               int* __restrict__ offs, int n)
{
    __shared__ int wsum[16];
    __shared__ int wpre[16];
    int tid = threadIdx.x, lane = tid & 63, wid = tid >> 6;
    int per = (n + 1023) / 1024;
    int start = tid * per, end = min(start + per, n);
    int sum = 0;
    for (int i = start; i < end; i++) sum += counts[i];
    int v = sum;
#pragma unroll
    for (int d = 1; d < 64; d <<= 1) {
        int t = __shfl_up(v, (unsigned)d, 64);
        if (lane >= d) v += t;
    }
    if (lane == 63) wsum[wid] = v;
    __syncthreads();
    if (tid == 0) {
        int acc = 0;
        for (int i = 0; i < 16; i++) { wpre[i] = acc; acc += wsum[i]; }
    }
    __syncthreads();
    int pre = wpre[wid] + v - sum;
    for (int i = start; i < end; i++) { offs[i] = pre; pre += counts[i]; }
    if (end == n && start <= n) offs[n] = pre;
}

// atomic-free: position = segment offset + precomputed rank
// R13: also writes 8 pad entries (src=0, attr=0) past the end so attn can
// load full batches unconditionally (pad scores forced to -inf in attn).
__global__ void scatter_k(const int* __restrict__ src, const int* __restrict__ dst,
                          const float* __restrict__ attr, const int* __restrict__ offs,
                          const int* __restrict__ rank, int2* __restrict__ edat, int E)
{
    int e = blockIdx.x * 256 + threadIdx.x;
    if (e < 8) edat[E + e] = make_int2(0, 0);
    if (e < E) {
        int p = offs[dst[e]] + rank[e];
        edat[p] = make_int2(src[e], __float_as_int(attr[e]));
    }
}

// ---------------- attention: one wave per dst node, batched online softmax ----
// R9-MEASURED VERSION, EXACT SOURCE (100.5us, VGPR=64, SGPR=80, occ 34%).
// DO NOT REPHRASE THIS LOOP. R7 measured: rewriting the ping-pong with a
// runtime curB bool selecting buffers cost +8 VGPR (64->72) -> 7 waves/SIMD
// -> 117us. The statically-unrolled two-phase body below is load-bearing.
// HARD CONSTRAINT (R5/R6/R7): VGPR <= 64 — kernel is TLP-limited.
__global__ __launch_bounds__(256) void attn_k(
    const uint2* __restrict__ q2, const uint2* __restrict__ kv8u2,
    const float* __restrict__ We,
    __half* __restrict__ hwork, const int2* __restrict__ edat,
    const int* __restrict__ offs,
    double* __restrict__ stats, int n, int nGroups)
{
    int lane = threadIdx.x & 63;
    int wid = threadIdx.x >> 6;
    float4 we = ((const float4*)We)[lane];
    float tsum = 0.f, tsq = 0.f;

    for (int g = blockIdx.x; g < nGroups; g += gridDim.x) {
        int node = g * 4 + wid;
        if (node >= n) continue;
        float4 qv = h4_to_f4(q2[(size_t)node * 256 + lane]);
        float qwe = qv.x * we.x + qv.y * we.y + qv.z * we.z + qv.w * we.w;
        qwe += __shfl_xor(qwe, 1);
        qwe += __shfl_xor(qwe, 2);
        qwe += __shfl_xor(qwe, 4);

        float4 accv = make_float4(0.f, 0.f, 0.f, 0.f);
        float sat = 0.f;
        float m = -INFINITY, l = 0.f;
        int i0 = __builtin_amdgcn_readfirstlane(offs[node]);
        int i1 = __builtin_amdgcn_readfirstlane(offs[node + 1]);

        int abA[8], srA[8], abB[8], srB[8];   // SGPR: attr bits / src index
        uint2 kvA[8], kvB[8];

        auto LOADB = [&](int base, int* ab_, int* sr_, uint2* kv_) {
#pragma unroll
            for (int u = 0; u < 8; u++) {
                int2 ed = edat[base + u];                     // uniform addr
                sr_[u] = __builtin_amdgcn_readfirstlane(ed.x);
                ab_[u] = __builtin_amdgcn_readfirstlane(ed.y);
            }
#pragma unroll
            for (int u = 0; u < 8; u++)
                kv_[u] = (kv8u2 + (size_t)(unsigned)sr_[u] * 64)[lane];
        };

        auto COMPUTE = [&](const int* ab_, const uint2* kv_, int cnt) {
            float pv[8];
#pragma unroll
            for (int u = 0; u < 8; u++) {
                float4 kvf = fp8x4_to_f4(kv_[u].x);
                float p = qv.x * kvf.x + qv.y * kvf.y + qv.z * kvf.z + qv.w * kvf.w;
                p += __shfl_xor(p, 1);
                p += __shfl_xor(p, 2);
                p += __shfl_xor(p, 4);
                p = fmaf(__int_as_float(ab_[u]), qwe, p) * 0.17677669529663687f;
                pv[u] = (u < cnt) ? p : -INFINITY;            // folds away for cnt=8
            }
            float m01 = fmaxf(pv[0], pv[1]), m23 = fmaxf(pv[2], pv[3]);
            float m45 = fmaxf(pv[4], pv[5]), m67 = fmaxf(pv[6], pv[7]);
            float pmax = fmaxf(fmaxf(m01, m23), fmaxf(m45, m67));
            float mn = fmaxf(m, pmax);
            float corr = __expf(m - mn);
            l *= corr;
            sat *= corr;
            accv.x *= corr; accv.y *= corr; accv.z *= corr; accv.w *= corr;
#pragma unroll
            for (int u = 0; u < 8; u++) {
                float wgt = __expf(pv[u] - mn);               // pad: exp(-inf)=0
                l += wgt;
                sat = fmaf(wgt, __int_as_float(ab_[u]), sat);
                float4 vv = fp8x4_to_f4(kv_[u].y);
                accv.x = fmaf(wgt, vv.x, accv.x);
                accv.y = fmaf(wgt, vv.y, accv.y);
                accv.z = fmaf(wgt, vv.z, accv.z);
                accv.w = fmaf(wgt, vv.w, accv.w);
            }
            m = mn;
        };

        if (i0 < i1) {
            int i = i0;
            LOADB(i, abA, srA, kvA);
            while (true) {
                if (i + 8 >= i1) { COMPUTE(abA, kvA, i1 - i); break; }
                LOADB(i + 8, abB, srB, kvB);
                COMPUTE(abA, kvA, 8);
                i += 8;
                if (i + 8 >= i1) { COMPUTE(abB, kvB, i1 - i); break; }
                LOADB(i + 8, abA, srA, kvA);
                COMPUTE(abB, kvB, 8);
                i += 8;
            }
        }

        float inv = (l > 0.f) ? 1.f / l : 0.f;
        float4 sk = h4_to_f4(q2[(size_t)node * 256 + 192 + lane]);
        float sw = sat * inv;
        float4 o;
        o.x = fmaf(accv.x, inv, fmaf(sw, we.x, sk.x));
        o.y = fmaf(accv.y, inv, fmaf(sw, we.y, sk.y));
        o.z = fmaf(accv.z, inv, fmaf(sw, we.z, sk.z));
        o.w = fmaf(accv.w, inv, fmaf(sw, we.w, sk.w));
        store4(hwork + (size_t)node * 256 + lane * 4, o);
        tsum += o.x + o.y + o.z + o.w;
        tsq += o.x * o.x + o.y * o.y + o.z * o.z + o.w * o.w;
    }

#pragma unroll
    for (int d = 1; d < 64; d <<= 1) {
        tsum += __shfl_xor(tsum, d);
        tsq += __shfl_xor(tsq, d);
    }
    __shared__ float red[8];
    if (lane == 0) { red[wid] = tsum; red[4 + wid] = tsq; }
    __syncthreads();
    if (threadIdx.x == 0) {
        double s = (double)red[0] + (double)red[1] + (double)red[2] + (double)red[3];
        double sq = (double)red[4] + (double)red[5] + (double)red[6] + (double)red[7];
        atomicAdd(&stats[0], s);
        atomicAdd(&stats[1], sq);
    }
}

// ---------------- LayerNorm apply (f16 in, f16 out; 4 elems/thread) ----------------
__global__ __launch_bounds__(256) void ln_apply(
    const uint2* __restrict__ in, __half* __restrict__ out,
    const float4* __restrict__ w4, const float4* __restrict__ b4,
    const double* __restrict__ stats, double cnt, int total4)
{
    int base = (blockIdx.x * 256 + threadIdx.x) * 4;
    if (base >= total4) return;
    double mu = stats[0] / cnt;
    double var = stats[1] / cnt - mu * mu;
    if (var < 0.0) var = 0.0;
    float mean = (float)mu;
    float inv = (float)(1.0 / (sqrt(var) + (double)EPSLN));
#pragma unroll
    for (int u = 0; u < 4; u++) {
        int i = base + u;
        if (i >= total4) return;
        int c = i & 63;
        float4 xv = h4_to_f4(in[i]);
        float4 w = w4[c], b = b4[c];
        float4 o;
        o.x = fmaf((xv.x - mean) * inv, w.x, b.x);
        o.y = fmaf((xv.y - mean) * inv, w.y, b.y);
        o.z = fmaf((xv.z - mean) * inv, w.z, b.z);
        o.w = fmaf((xv.w - mean) * inv, w.w, b.w);
        o.x = o.x > 0.f ? o.x : expm1f(o.x);
        o.y = o.y > 0.f ? o.y : expm1f(o.y);
        o.z = o.z > 0.f ? o.z : expm1f(o.z);
        o.w = o.w > 0.f ? o.w : expm1f(o.w);
        store4(out + (size_t)i * 4, o);
    }
}

// ---------------- driver ----------------
extern "C" void kernel_launch(void* const* d_in, const int* in_sizes, int n_in,
                              void* d_out, int out_size, void* d_ws, size_t ws_size,
                              hipStream_t stream)
{
    const float* x      = (const float*)d_in[0];
    const int*   ei     = (const int*)d_in[1];
    const float* eattr  = (const float*)d_in[2];
    const float* Wq1 = (const float*)d_in[3];  const float* bq1 = (const float*)d_in[4];
    const float* Wk1 = (const float*)d_in[5];  const float* bk1 = (const float*)d_in[6];
    const float* Wv1 = (const float*)d_in[7];  const float* bv1 = (const float*)d_in[8];
    const float* We1 = (const float*)d_in[9];
    const float* Ws1 = (const float*)d_in[10]; const float* bs1 = (const float*)d_in[11];
    const float* lnw1 = (const float*)d_in[12]; const float* lnb1 = (const float*)d_in[13];
    const float* Wq2 = (const float*)d_in[14]; const float* bq2 = (const float*)d_in[15];
    const float* Wk2 = (const float*)d_in[16]; const float* bk2 = (const float*)d_in[17];
    const float* Wv2 = (const float*)d_in[18]; const float* bv2 = (const float*)d_in[19];
    const float* We2 = (const float*)d_in[20];
    const float* Ws2 = (const float*)d_in[21]; const float* bs2 = (const float*)d_in[22];
    const float* lnw2 = (const float*)d_in[23]; const float* lnb2 = (const float*)d_in[24];
    const float* Wo  = (const float*)d_in[25]; const float* bo  = (const float*)d_in[26];

    const int N = in_sizes[0] / IN_DIM;
    const int E = in_sizes[2];
    const int* esrc = ei;
    const int* edst = ei + E;

    char* ws = (char*)d_ws;
    size_t off = 0;
    auto alloc = [&](size_t bytes) -> char* {
        char* p = ws + off;
        off += (bytes + 255) / 256 * 256;
        return p;
    };
    int*    counts = (int*)alloc((size_t)N * 4);
    double* stats  = (double*)alloc(64);
    size_t zbytes = off;
    int*    rank   = (int*)alloc((size_t)E * 4);
    int*    offs   = (int*)alloc((size_t)(N + 1) * 4);
    int2*   edat   = (int2*)alloc((size_t)(E + 8) * 8);
    __half* xh     = (__half*)alloc((size_t)N * IN_DIM * 2);
    __half* qkvs   = (__half*)alloc((size_t)N * 1024 * 2);
    unsigned char* kv8 = (unsigned char*)alloc((size_t)N * 512);
    __half* hwork  = (__half*)alloc((size_t)N * HD * 2);
    __half* hio    = (__half*)alloc((size_t)N * HD * 2);
    __half* Wc1    = (__half*)alloc((size_t)1024 * IN_DIM * 2);
    __half* Wc2    = (__half*)alloc((size_t)1024 * HD * 2);
    __half* Wot    = (__half*)alloc((size_t)64 * HD * 2);
    float*  bc1    = (float*)alloc(1024 * 4);
    float*  bc2    = (float*)alloc(1024 * 4);

    hipMemsetAsync(d_ws, 0, zbytes, stream);

    int total4x = N * (IN_DIM / 4);
    int prepWork = total4x > E ? total4x : E;
    if (prepWork < 411648) prepWork = 411648;
    prep_k<<<(prepWork + 255) / 256, 256, 0, stream>>>(
        (const float4*)x, xh, total4x, edst, counts, rank, E,
        Wq1, Wk1, Wv1, Ws1, Wq2, Wk2, Wv2, Ws2, Wo,
        bq1, bk1, bv1, bs1, bq2, bk2, bv2, bs2,
        Wc1, Wc2, Wot, bc1, bc2);

    scan_k<<<1, 1024, 0, stream>>>(counts, offs, N);
    scatter_k<<<(E + 255) / 256, 256, 0, stream>>>(esrc, edst, eattr, offs, rank,
                                                   edat, E);

    int nbx = (N + BM - 1) / BM;
    dim3 gqkvs(nbx * 8);                              // 1-D grid for XCD swizzle
    int nGroups = (N + 3) / 4;
    int gaBlocks = nGroups < 2048 ? nGroups : 2048;   // persistent blocks (proven R8 config)
    int total4 = N * (HD / 4);
    dim3 gl((total4 / 4 + 255) / 256);
    dim3 gout((N + 127) / 128);

    // ---- layer 1 ----
    gemm_mfma<<<gqkvs, 256, 0, stream>>>(xh, Wc1, bc1, qkvs, kv8, N, IN_DIM, 1024);
    attn_k<<<gaBlocks, 256, 0, stream>>>((const uint2*)qkvs, (const uint2*)kv8, We1,
                                         hwork, edat, offs, stats, N, nGroups);
    ln_apply<<<gl, 256, 0, stream>>>((const uint2*)hwork, hio,
                                     (const float4*)lnw1, (const float4*)lnb1,
                                     stats, (double)N * HD, total4);

    // ---- layer 2 ----
    gemm_mfma<<<gqkvs, 256, 0, stream>>>(hio, Wc2, bc2, qkvs, kv8, N, HD, 1024);
    attn_k<<<gaBlocks, 256, 0, stream>>>((const uint2*)qkvs, (const uint2*)kv8, We2,
                                         hwork, edat, offs, stats + 2, N, nGroups);
    ln_apply<<<gl, 256, 0, stream>>>((const uint2*)hwork, hio,
                                     (const float4*)lnw2, (const float4*)lnb2,
                                     stats + 2, (double)N * HD, total4);

    // ---- output projection (fp32 out, dedicated 128x64 kernel) ----
    gemm_out_k<<<gout, 256, 0, stream>>>(hio, Wot, bo, (float*)d_out, N);
}

// Round 12
// 487.112 us; speedup vs baseline: 3.4502x; 1.1782x over previous
//
#include <hip/hip_runtime.h>
#include <hip/hip_fp16.h>
#include <math.h>

#define IN_DIM 128
#define HD 256
#define EPSLN 1e-5f

typedef _Float16 half8 __attribute__((ext_vector_type(8)));
typedef float f32x4 __attribute__((ext_vector_type(4)));
typedef float f32x2 __attribute__((ext_vector_type(2)));

// ---------------- helpers ----------------
__device__ inline void store4(float* p, float4 o) { *(float4*)p = o; }
__device__ inline void store4(__half* p, float4 o) {
    union { uint2 u; __half2 h[2]; } s;
    s.h[0] = __floats2half2_rn(o.x, o.y);
    s.h[1] = __floats2half2_rn(o.z, o.w);
    *(uint2*)p = s.u;
}
__device__ inline float4 h4_to_f4(uint2 u) {
    union { unsigned int w; __half2 h; } a, b;
    a.w = u.x; b.w = u.y;
    float2 lo = __half22float2(a.h), hi = __half22float2(b.h);
    return make_float4(lo.x, lo.y, hi.x, hi.y);
}
// 4 floats -> 4 packed fp8 e4m3 (OCP, gfx950 HW cvt)
__device__ inline unsigned int f4_to_fp8x4(float a, float b, float c, float d) {
    int v = 0;
    v = __builtin_amdgcn_cvt_pk_fp8_f32(a, b, v, false);
    v = __builtin_amdgcn_cvt_pk_fp8_f32(c, d, v, true);
    return (unsigned int)v;
}
__device__ inline float4 fp8x4_to_f4(unsigned int u) {
    f32x2 lo = __builtin_amdgcn_cvt_pk_f32_fp8((int)u, false);
    f32x2 hi = __builtin_amdgcn_cvt_pk_f32_fp8((int)u, true);
    return make_float4(lo.x, lo.y, hi.x, hi.y);
}

__device__ inline void async_copy16(const __half* g, _Float16* l) {
    __builtin_amdgcn_global_load_lds(
        (const __attribute__((address_space(1))) void*)g,
        (__attribute__((address_space(3))) void*)l,
        16, 0, 0);
}

// Packed output column mapping: q[0:256) | kv-interleaved[256:768) | skip[768:1024)
__device__ inline void unpermute_col(int n, int& sel, int& c) {
    if (n < 256) { sel = 0; c = n; }
    else if (n < 768) {
        int j = n - 256, chunk = j >> 3, w = j & 7;
        if (w < 4) { sel = 1; c = chunk * 4 + w; }
        else       { sel = 2; c = chunk * 4 + w - 4; }
    } else { sel = 3; c = n - 768; }
}

// ---------------- fused prep: pack x, pack weights/biases, count degrees + ranks ----
__global__ void prep_k(
    const float4* __restrict__ x, __half* __restrict__ xh, int total4,
    const int* __restrict__ dst, int* __restrict__ counts, int* __restrict__ rank, int E,
    const float* __restrict__ Wq1, const float* __restrict__ Wk1,
    const float* __restrict__ Wv1, const float* __restrict__ Ws1,
    const float* __restrict__ Wq2, const float* __restrict__ Wk2,
    const float* __restrict__ Wv2, const float* __restrict__ Ws2,
    const float* __restrict__ Wo,
    const float* __restrict__ bq1, const float* __restrict__ bk1,
    const float* __restrict__ bv1, const float* __restrict__ bs1,
    const float* __restrict__ bq2, const float* __restrict__ bk2,
    const float* __restrict__ bv2, const float* __restrict__ bs2,
    __half* __restrict__ Wc1, __half* __restrict__ Wc2, __half* __restrict__ Wot,
    float* __restrict__ bc1, float* __restrict__ bc2)
{
    int idx = blockIdx.x * 256 + threadIdx.x;
    if (idx < total4) store4(xh + (size_t)idx * 4, x[idx]);
    if (idx < E) rank[idx] = atomicAdd(&counts[dst[idx]], 1);   // rank within dst bucket
    if (idx < 131072) {
        int n = idx >> 7, k = idx & 127;
        int sel, c; unpermute_col(n, sel, c);
        const float* W = (sel == 0) ? Wq1 : (sel == 1) ? Wk1 : (sel == 2) ? Wv1 : Ws1;
        Wc1[idx] = __float2half(W[(size_t)k * 256 + c]);
    } else if (idx < 393216) {
        int j = idx - 131072;
        int n = j >> 8, k = j & 255;
        int sel, c; unpermute_col(n, sel, c);
        const float* W = (sel == 0) ? Wq2 : (sel == 1) ? Wk2 : (sel == 2) ? Wv2 : Ws2;
        Wc2[j] = __float2half(W[(size_t)k * 256 + c]);
    } else if (idx < 409600) {
        int j = idx - 393216;
        int n = j >> 8, k = j & 255;
        Wot[j] = __float2half(Wo[(size_t)k * 64 + n]);
    } else if (idx < 410624) {
        int n = idx - 409600;
        int sel, c; unpermute_col(n, sel, c);
        const float* b = (sel == 0) ? bq1 : (sel == 1) ? bk1 : (sel == 2) ? bv1 : bs1;
        bc1[n] = b[c];
    } else if (idx < 411648) {
        int n = idx - 410624;
        int sel, c; unpermute_col(n, sel, c);
        const float* b = (sel == 0) ? bq2 : (sel == 1) ? bk2 : (sel == 2) ? bv2 : bs2;
        bc2[n] = b[c];
    }
}

// ---------------- MFMA GEMM: C[M x Nc] = A[M x K] @ Wt^T + bias (f16 out) ----------------
// R13: 1-D grid + XCD-grouping swizzle (measured R4: ~44us win across both gemms).
// R17/R18: BK=32 single-barrier double-buffer (measured R11: neutral-to-slightly-
// positive vs 2-barrier; kept as the verified config). LDS: As0@0, Bs0@8K,
// As1@16K, Bs1@24K within the 34,816B epilogue region. Buffer bases computed
// per-use (LDS pointer arrays fail to compile on gfx950 — R10 lesson).
#define BM 128
#define BN 128
#define TROWB 272   // f16 out-tile row stride (bytes)

__global__ __launch_bounds__(256) void gemm_mfma(
    const __half* __restrict__ A, const __half* __restrict__ Wt,
    const float* __restrict__ bias, __half* __restrict__ C,
    unsigned char* __restrict__ kv8,
    int M, int K, int Nc)
{
    __shared__ char smem[BM * TROWB];          // 34,816 B; dbuf overlaid below

    int tid = threadIdx.x;
    int lane = tid & 63, w = tid >> 6;
    int wm = w >> 1, wn = w & 1;
    int quad = lane >> 4, l16 = lane & 15;
    // XCD swizzle: nwg = nbx*8 (exact multiple of 8 XCDs)
    int nbx = (int)gridDim.x >> 3;
    int wkr = ((int)blockIdx.x & 7) * nbx + ((int)blockIdx.x >> 3);
    int row0 = (wkr >> 3) * BM;
    int col0 = (wkr & 7) * BN;

    f32x4 acc[4][4];
#pragma unroll
    for (int i = 0; i < 4; i++)
#pragma unroll
        for (int j = 0; j < 4; j++) acc[i][j] = (f32x4){0.f, 0.f, 0.f, 0.f};

    int srow = lane >> 2;      // 0..15 (16 rows per wave-instruction at BK=32)
    int schunk = lane & 3;     // 4 chunks of 8 f16 per 64B row

    int nt = K >> 5;           // K/32 steps

    // STAGE(step, buf): issue A+B tile loads for k0 = step*32 into buffer buf
    auto STAGE = [&](int step, int buf) {
        int k0 = step << 5;
        _Float16* Asb = (_Float16*)(smem + buf * 16384);
        _Float16* Bsb = (_Float16*)(smem + 8192 + buf * 16384);
#pragma unroll
        for (int t = 0; t < 2; t++) {
            int r = w * 32 + t * 16 + srow;
            int gr = row0 + r; if (gr > M - 1) gr = M - 1;
            int gchunk = schunk ^ ((r ^ (r >> 2)) & 3);
            async_copy16(&A[(size_t)gr * K + k0 + gchunk * 8], &Asb[(w * 32 + t * 16) * 32]);
        }
#pragma unroll
        for (int t = 0; t < 2; t++) {
            int r = w * 32 + t * 16 + srow;
            int gc = col0 + r; if (gc > Nc - 1) gc = Nc - 1;
            int gchunk = schunk ^ ((r ^ (r >> 2)) & 3);
            async_copy16(&Wt[(size_t)gc * K + k0 + gchunk * 8], &Bsb[(w * 32 + t * 16) * 32]);
        }
    };

    STAGE(0, 0);
    __syncthreads();

    for (int t = 0; t < nt; ++t) {
        if (t + 1 < nt) STAGE(t + 1, (t + 1) & 1);
        _Float16* Asb = (_Float16*)(smem + (t & 1) * 16384);
        _Float16* Bsb = (_Float16*)(smem + 8192 + (t & 1) * 16384);
        half8 af[4], bf[4];
#pragma unroll
        for (int i = 0; i < 4; i++) {
            int ra = wm * 64 + i * 16 + l16;
            af[i] = *(half8*)&Asb[ra * 32 + ((quad ^ ((ra ^ (ra >> 2)) & 3)) * 8)];
            int rb = wn * 64 + i * 16 + l16;
            bf[i] = *(half8*)&Bsb[rb * 32 + ((quad ^ ((rb ^ (rb >> 2)) & 3)) * 8)];
        }
#pragma unroll
        for (int i = 0; i < 4; i++)
#pragma unroll
            for (int j = 0; j < 4; j++)
                acc[i][j] = __builtin_amdgcn_mfma_f32_16x16x32_f16(af[i], bf[j], acc[i][j], 0, 0, 0);
        __syncthreads();
    }

#pragma unroll
    for (int j = 0; j < 4; j++) {
        int tcol = wn * 64 + j * 16 + l16;
        float bb = (col0 + tcol < Nc) ? bias[col0 + tcol] : 0.f;
#pragma unroll
        for (int i = 0; i < 4; i++) {
#pragma unroll
            for (int r = 0; r < 4; r++) {
                int trow = wm * 64 + i * 16 + quad * 4 + r;
                ((__half*)(smem + trow * TROWB))[tcol] = __float2half(acc[i][j][r] + bb);
            }
        }
    }
    __syncthreads();
    bool iskv = (col0 >= 256) && (col0 < 768);
    int crow = tid >> 4, cchunk = tid & 15;
    for (int p = 0; p < 8; p++) {
        int trow = p * 16 + crow;
        int grow = row0 + trow;
        if (grow >= M) continue;
        uint4 val = *(uint4*)(smem + trow * TROWB + cchunk * 16);
        if (iskv) {
            float4 lo = h4_to_f4(make_uint2(val.x, val.y));
            float4 hi = h4_to_f4(make_uint2(val.z, val.w));
            uint2 o8;
            o8.x = f4_to_fp8x4(lo.x, lo.y, lo.z, lo.w);
            o8.y = f4_to_fp8x4(hi.x, hi.y, hi.z, hi.w);
            *(uint2*)&kv8[(size_t)grow * 512 + (col0 - 256) + cchunk * 8] = o8;
        } else {
            *(uint4*)&C[(size_t)grow * Nc + col0 + cchunk * 8] = val;
        }
    }
}

// ---------------- output GEMM: D[M x 64] = A[M x 256] @ Wot^T + bo (fp32 out) ----------
// R17/R18: BK=32 single-barrier double-buffer. LDS 24KB.
// Layout (halfs): As0@0 (4096), As1@4096, Bs0@8192 (2048), Bs1@10240.
__global__ __launch_bounds__(256) void gemm_out_k(
    const __half* __restrict__ A, const __half* __restrict__ Wot,
    const float* __restrict__ bias, float* __restrict__ D, int M)
{
    __shared__ _Float16 smem[12288];   // 24 KB
    int tid = threadIdx.x;
    int lane = tid & 63, w = tid >> 6;
    int quad = lane >> 4, l16 = lane & 15;
    int row0 = blockIdx.x * 128;
    const int K = 256;

    f32x4 acc[2][4];
#pragma unroll
    for (int i = 0; i < 2; i++)
#pragma unroll
        for (int j = 0; j < 4; j++) acc[i][j] = (f32x4){0.f, 0.f, 0.f, 0.f};

    int srow = lane >> 2;
    int schunk = lane & 3;
    const int nt = 8;   // 256/32

    auto STAGE = [&](int step, int buf) {
        int k0 = step << 5;
        _Float16* Asb = smem + buf * 4096;
        _Float16* Bsb = smem + 8192 + buf * 2048;
#pragma unroll
        for (int t = 0; t < 2; t++) {
            int r = w * 32 + t * 16 + srow;
            int gr = row0 + r; if (gr > M - 1) gr = M - 1;
            int gchunk = schunk ^ ((r ^ (r >> 2)) & 3);
            async_copy16(&A[(size_t)gr * K + k0 + gchunk * 8], &Asb[(w * 32 + t * 16) * 32]);
        }
        {
            int r = w * 16 + srow;       // 64 weight rows, one wave-inst per wave
            int gchunk = schunk ^ ((r ^ (r >> 2)) & 3);
            async_copy16(&Wot[(size_t)r * K + k0 + gchunk * 8], &Bsb[(w * 16) * 32]);
        }
    };

    STAGE(0, 0);
    __syncthreads();

    for (int t = 0; t < nt; ++t) {
        if (t + 1 < nt) STAGE(t + 1, (t + 1) & 1);
        _Float16* Asb = smem + (t & 1) * 4096;
        _Float16* Bsb = smem + 8192 + (t & 1) * 2048;
        half8 af[2], bf[4];
#pragma unroll
        for (int i = 0; i < 2; i++) {
            int ra = w * 32 + i * 16 + l16;
            af[i] = *(half8*)&Asb[ra * 32 + ((quad ^ ((ra ^ (ra >> 2)) & 3)) * 8)];
        }
#pragma unroll
        for (int j = 0; j < 4; j++) {
            int rb = j * 16 + l16;
            bf[j] = *(half8*)&Bsb[rb * 32 + ((quad ^ ((rb ^ (rb >> 2)) & 3)) * 8)];
        }
#pragma unroll
        for (int i = 0; i < 2; i++)
#pragma unroll
            for (int j = 0; j < 4; j++)
                acc[i][j] = __builtin_amdgcn_mfma_f32_16x16x32_f16(af[i], bf[j], acc[i][j], 0, 0, 0);
        __syncthreads();
    }

#pragma unroll
    for (int i = 0; i < 2; i++) {
#pragma unroll
        for (int j = 0; j < 4; j++) {
            int gcol = j * 16 + l16;
            float bb = bias[gcol];
#pragma unroll
            for (int r = 0; r < 4; r++) {
                int grow = row0 + w * 32 + i * 16 + quad * 4 + r;
                if (grow < M) D[(size_t)grow * 64 + gcol] = acc[i][j][r] + bb;
            }
        }
    }
}

// ---------------- edge bucketing: 3-phase parallel scan (R19) ----------------
// The old single-block scan_k walked ~49 sequential dependent L2 loads per
// thread (~15-25us serial latency). Now: 98 blocks of partials -> 128-thread
// top prefix -> parallel fix + offs write. Each phase is latency-flat.
__global__ __launch_bounds__(256) void scan_part_k(const int* __restrict__ counts,
                                                   int* __restrict__ part, int n)
{
    int b = blockIdx.x, t = threadIdx.x;
    int i0 = b * 512 + t * 2;
    int s = 0;
    if (i0 < n) s += counts[i0];
    if (i0 + 1 < n) s += counts[i0 + 1];
    int lane = t & 63, wid = t >> 6;
    int v = s;
#pragma unroll
    for (int d = 1; d < 64; d <<= 1) v += __shfl_xor(v, d);
    __shared__ int ws[4];
    if (lane == 0) ws[wid] = v;
    __syncthreads();
    if (t == 0) part[b] = ws[0] + ws[1] + ws[2] + ws[3];
}

__global__ __launch_bounds__(128) void scan_top_k(int* __restrict__ part, int nb)
{
    // exclusive prefix over nb (<=128) entries, in place
    int t = threadIdx.x, lane = t & 63, wid = t >> 6;
    int orig = (t < nb) ? part[t] : 0;
    int v = orig;
#pragma unroll
    for (int d = 1; d < 64; d <<= 1) {
        int u = __shfl_up(v, (unsigned)d, 64);
        if (lane >= d) v += u;
    }
    __shared__ int wsum[2];
    if (lane == 63) wsum[wid] = v;
    __syncthreads();
    int add = (wid == 1) ? wsum[0] : 0;
    if (t < nb) part[t] = v + add - orig;   // exclusive base
}

__global__ __launch_bounds__(256) void scan_fix_k(const int* __restrict__ counts,
                                                  const int* __restrict__ part,
                                                  int* __restrict__ offs, int n)
{
    int b = blockIdx.x, t = threadIdx.x;
    int lane = t & 63, wid = t >> 6;
    int i0 = b * 512 + t * 2;
    int c0 = (i0 < n) ? counts[i0] : 0;
    int c1 = (i0 + 1 < n) ? counts[i0 + 1] : 0;
    int s = c0 + c1;
    int v = s;
#pragma unroll
    for (int d = 1; d < 64; d <<= 1) {
        int u = __shfl_up(v, (unsigned)d, 64);
        if (lane >= d) v += u;
    }
    __shared__ int wsum[4], wpre[4];
    if (lane == 63) wsum[wid] = v;
    __syncthreads();
    if (t == 0) { int a = 0; for (int i = 0; i < 4; i++) { wpre[i] = a; a += wsum[i]; } }
    __syncthreads();
    int pre = part[b] + wpre[wid] + v - s;   // exclusive prefix for this thread
    if (i0 < n) offs[i0] = pre;
    if (i0 + 1 < n) offs[i0 + 1] = pre + c0;
    int end = i0 + 2; if (end > n) end = n;
    if (end == n) offs[n] = pre + c0 + c1;   // racing writers all write the total
}

// atomic-free: position = segment offset + precomputed rank
// R13: also writes 8 pad entries (src=0, attr=0) past the end so attn can
// load full batches unconditionally (pad scores forced to -inf in attn).
__global__ void scatter_k(const int* __restrict__ src, const int* __restrict__ dst,
                          const float* __restrict__ attr, const int* __restrict__ offs,
                          const int* __restrict__ rank, int2* __restrict__ edat, int E)
{
    int e = blockIdx.x * 256 + threadIdx.x;
    if (e < 8) edat[E + e] = make_int2(0, 0);
    if (e < E) {
        int p = offs[dst[e]] + rank[e];
        edat[p] = make_int2(src[e], __float_as_int(attr[e]));
    }
}

// ---------------- attention: one wave per dst node, batched online softmax ----
// R9-MEASURED VERSION, EXACT SOURCE (100.5us, VGPR=64, SGPR=80, occ 34%).
// DO NOT REPHRASE THIS LOOP. R7 measured: rewriting the ping-pong with a
// runtime curB bool selecting buffers cost +8 VGPR (64->72) -> 7 waves/SIMD
// -> 117us. The statically-unrolled two-phase body below is load-bearing.
// HARD CONSTRAINT (R5/R6/R7): VGPR <= 64 — kernel is TLP-limited (at 64 VGPR,
// 8 waves/SIMD = architectural max occupancy).
__global__ __launch_bounds__(256) void attn_k(
    const uint2* __restrict__ q2, const uint2* __restrict__ kv8u2,
    const float* __restrict__ We,
    __half* __restrict__ hwork, const int2* __restrict__ edat,
    const int* __restrict__ offs,
    double* __restrict__ stats, int n, int nGroups)
{
    int lane = threadIdx.x & 63;
    int wid = threadIdx.x >> 6;
    float4 we = ((const float4*)We)[lane];
    float tsum = 0.f, tsq = 0.f;

    for (int g = blockIdx.x; g < nGroups; g += gridDim.x) {
        int node = g * 4 + wid;
        if (node >= n) continue;
        float4 qv = h4_to_f4(q2[(size_t)node * 256 + lane]);
        float qwe = qv.x * we.x + qv.y * we.y + qv.z * we.z + qv.w * we.w;
        qwe += __shfl_xor(qwe, 1);
        qwe += __shfl_xor(qwe, 2);
        qwe += __shfl_xor(qwe, 4);

        float4 accv = make_float4(0.f, 0.f, 0.f, 0.f);
        float sat = 0.f;
        float m = -INFINITY, l = 0.f;
        int i0 = __builtin_amdgcn_readfirstlane(offs[node]);
        int i1 = __builtin_amdgcn_readfirstlane(offs[node + 1]);

        int abA[8], srA[8], abB[8], srB[8];   // SGPR: attr bits / src index
        uint2 kvA[8], kvB[8];

        auto LOADB = [&](int base, int* ab_, int* sr_, uint2* kv_) {
#pragma unroll
            for (int u = 0; u < 8; u++) {
                int2 ed = edat[base + u];                     // uniform addr
                sr_[u] = __builtin_amdgcn_readfirstlane(ed.x);
                ab_[u] = __builtin_amdgcn_readfirstlane(ed.y);
            }
#pragma unroll
            for (int u = 0; u < 8; u++)
                kv_[u] = (kv8u2 + (size_t)(unsigned)sr_[u] * 64)[lane];
        };

        auto COMPUTE = [&](const int* ab_, const uint2* kv_, int cnt) {
            float pv[8];
#pragma unroll
            for (int u = 0; u < 8; u++) {
                float4 kvf = fp8x4_to_f4(kv_[u].x);
                float p = qv.x * kvf.x + qv.y * kvf.y + qv.z * kvf.z + qv.w * kvf.w;
                p += __shfl_xor(p, 1);
                p += __shfl_xor(p, 2);
                p += __shfl_xor(p, 4);
                p = fmaf(__int_as_float(ab_[u]), qwe, p) * 0.17677669529663687f;
                pv[u] = (u < cnt) ? p : -INFINITY;            // folds away for cnt=8
            }
            float m01 = fmaxf(pv[0], pv[1]), m23 = fmaxf(pv[2], pv[3]);
            float m45 = fmaxf(pv[4], pv[5]), m67 = fmaxf(pv[6], pv[7]);
            float pmax = fmaxf(fmaxf(m01, m23), fmaxf(m45, m67));
            float mn = fmaxf(m, pmax);
            float corr = __expf(m - mn);
            l *= corr;
            sat *= corr;
            accv.x *= corr; accv.y *= corr; accv.z *= corr; accv.w *= corr;
#pragma unroll
            for (int u = 0; u < 8; u++) {
                float wgt = __expf(pv[u] - mn);               // pad: exp(-inf)=0
                l += wgt;
                sat = fmaf(wgt, __int_as_float(ab_[u]), sat);
                float4 vv = fp8x4_to_f4(kv_[u].y);
                accv.x = fmaf(wgt, vv.x, accv.x);
                accv.y = fmaf(wgt, vv.y, accv.y);
                accv.z = fmaf(wgt, vv.z, accv.z);
                accv.w = fmaf(wgt, vv.w, accv.w);
            }
            m = mn;
        };

        if (i0 < i1) {
            int i = i0;
            LOADB(i, abA, srA, kvA);
            while (true) {
                if (i + 8 >= i1) { COMPUTE(abA, kvA, i1 - i); break; }
                LOADB(i + 8, abB, srB, kvB);
                COMPUTE(abA, kvA, 8);
                i += 8;
                if (i + 8 >= i1) { COMPUTE(abB, kvB, i1 - i); break; }
                LOADB(i + 8, abA, srA, kvA);
                COMPUTE(abB, kvB, 8);
                i += 8;
            }
        }

        float inv = (l > 0.f) ? 1.f / l : 0.f;
        float4 sk = h4_to_f4(q2[(size_t)node * 256 + 192 + lane]);
        float sw = sat * inv;
        float4 o;
        o.x = fmaf(accv.x, inv, fmaf(sw, we.x, sk.x));
        o.y = fmaf(accv.y, inv, fmaf(sw, we.y, sk.y));
        o.z = fmaf(accv.z, inv, fmaf(sw, we.z, sk.z));
        o.w = fmaf(accv.w, inv, fmaf(sw, we.w, sk.w));
        store4(hwork + (size_t)node * 256 + lane * 4, o);
        tsum += o.x + o.y + o.z + o.w;
        tsq += o.x * o.x + o.y * o.y + o.z * o.z + o.w * o.w;
    }

#pragma unroll
    for (int d = 1; d < 64; d <<= 1) {
        tsum += __shfl_xor(tsum, d);
        tsq += __shfl_xor(tsq, d);
    }
    __shared__ float red[8];
    if (lane == 0) { red[wid] = tsum; red[4 + wid] = tsq; }
    __syncthreads();
    if (threadIdx.x == 0) {
        double s = (double)red[0] + (double)red[1] + (double)red[2] + (double)red[3];
        double sq = (double)red[4] + (double)red[5] + (double)red[6] + (double)red[7];
        atomicAdd(&stats[0], s);
        atomicAdd(&stats[1], sq);
    }
}

// ---------------- LayerNorm apply (f16 in, f16 out; 8 elems/thread pairs) ----------------
// R19: stats-derived mean/inv computed ONCE per block in thread 0 (f64 divide/
// sqrt sequences are ~500cy microcode — was redundantly done by all 800K
// threads), LDS-broadcast. Loads/stores vectorized 16B.
__global__ __launch_bounds__(256) void ln_apply(
    const uint2* __restrict__ in, __half* __restrict__ out,
    const float4* __restrict__ w4, const float4* __restrict__ b4,
    const double* __restrict__ stats, double cnt, int total4)
{
    __shared__ float sm[2];
    if (threadIdx.x == 0) {
        double mu = stats[0] / cnt;
        double var = stats[1] / cnt - mu * mu;
        if (var < 0.0) var = 0.0;
        sm[0] = (float)mu;
        sm[1] = (float)(1.0 / (sqrt(var) + (double)EPSLN));
    }
    __syncthreads();
    int base = (blockIdx.x * 256 + threadIdx.x) * 4;
    if (base >= total4) return;
    float mean = sm[0];
    float inv = sm[1];

    uint4 ra = *(const uint4*)(in + base);        // i = base, base+1
    uint4 rb = *(const uint4*)(in + base + 2);    // i = base+2, base+3
    uint2 rw[4] = { make_uint2(ra.x, ra.y), make_uint2(ra.z, ra.w),
                    make_uint2(rb.x, rb.y), make_uint2(rb.z, rb.w) };
    uint2 ow[4];
#pragma unroll
    for (int u = 0; u < 4; u++) {
        int i = base + u;
        int c = i & 63;
        float4 xv = h4_to_f4(rw[u]);
        float4 w = w4[c], b = b4[c];
        float4 o;
        o.x = fmaf((xv.x - mean) * inv, w.x, b.x);
        o.y = fmaf((xv.y - mean) * inv, w.y, b.y);
        o.z = fmaf((xv.z - mean) * inv, w.z, b.z);
        o.w = fmaf((xv.w - mean) * inv, w.w, b.w);
        o.x = o.x > 0.f ? o.x : expm1f(o.x);
        o.y = o.y > 0.f ? o.y : expm1f(o.y);
        o.z = o.z > 0.f ? o.z : expm1f(o.z);
        o.w = o.w > 0.f ? o.w : expm1f(o.w);
        union { uint2 u2; __half2 h[2]; } s;
        s.h[0] = __floats2half2_rn(o.x, o.y);
        s.h[1] = __floats2half2_rn(o.z, o.w);
        ow[u] = s.u2;
    }
    uint4 s0 = make_uint4(ow[0].x, ow[0].y, ow[1].x, ow[1].y);
    uint4 s1 = make_uint4(ow[2].x, ow[2].y, ow[3].x, ow[3].y);
    *(uint4*)(out + (size_t)base * 4) = s0;
    *(uint4*)(out + (size_t)(base + 2) * 4) = s1;
}

// ---------------- driver ----------------
extern "C" void kernel_launch(void* const* d_in, const int* in_sizes, int n_in,
                              void* d_out, int out_size, void* d_ws, size_t ws_size,
                              hipStream_t stream)
{
    const float* x      = (const float*)d_in[0];
    const int*   ei     = (const int*)d_in[1];
    const float* eattr  = (const float*)d_in[2];
    const float* Wq1 = (const float*)d_in[3];  const float* bq1 = (const float*)d_in[4];
    const float* Wk1 = (const float*)d_in[5];  const float* bk1 = (const float*)d_in[6];
    const float* Wv1 = (const float*)d_in[7];  const float* bv1 = (const float*)d_in[8];
    const float* We1 = (const float*)d_in[9];
    const float* Ws1 = (const float*)d_in[10]; const float* bs1 = (const float*)d_in[11];
    const float* lnw1 = (const float*)d_in[12]; const float* lnb1 = (const float*)d_in[13];
    const float* Wq2 = (const float*)d_in[14]; const float* bq2 = (const float*)d_in[15];
    const float* Wk2 = (const float*)d_in[16]; const float* bk2 = (const float*)d_in[17];
    const float* Wv2 = (const float*)d_in[18]; const float* bv2 = (const float*)d_in[19];
    const float* We2 = (const float*)d_in[20];
    const float* Ws2 = (const float*)d_in[21]; const float* bs2 = (const float*)d_in[22];
    const float* lnw2 = (const float*)d_in[23]; const float* lnb2 = (const float*)d_in[24];
    const float* Wo  = (const float*)d_in[25]; const float* bo  = (const float*)d_in[26];

    const int N = in_sizes[0] / IN_DIM;
    const int E = in_sizes[2];
    const int* esrc = ei;
    const int* edst = ei + E;

    char* ws = (char*)d_ws;
    size_t off = 0;
    auto alloc = [&](size_t bytes) -> char* {
        char* p = ws + off;
        off += (bytes + 255) / 256 * 256;
        return p;
    };
    int*    counts = (int*)alloc((size_t)N * 4);
    double* stats  = (double*)alloc(64);
    size_t zbytes = off;
    int*    rank   = (int*)alloc((size_t)E * 4);
    int*    offs   = (int*)alloc((size_t)(N + 1) * 4);
    int2*   edat   = (int2*)alloc((size_t)(E + 8) * 8);
    __half* xh     = (__half*)alloc((size_t)N * IN_DIM * 2);
    __half* qkvs   = (__half*)alloc((size_t)N * 1024 * 2);
    unsigned char* kv8 = (unsigned char*)alloc((size_t)N * 512);
    __half* hwork  = (__half*)alloc((size_t)N * HD * 2);
    __half* hio    = (__half*)alloc((size_t)N * HD * 2);
    __half* Wc1    = (__half*)alloc((size_t)1024 * IN_DIM * 2);
    __half* Wc2    = (__half*)alloc((size_t)1024 * HD * 2);
    __half* Wot    = (__half*)alloc((size_t)64 * HD * 2);
    float*  bc1    = (float*)alloc(1024 * 4);
    float*  bc2    = (float*)alloc(1024 * 4);
    int*    part   = (int*)alloc(512);            // scan partials (<=128 blocks)

    hipMemsetAsync(d_ws, 0, zbytes, stream);

    int total4x = N * (IN_DIM / 4);
    int prepWork = total4x > E ? total4x : E;
    if (prepWork < 411648) prepWork = 411648;
    prep_k<<<(prepWork + 255) / 256, 256, 0, stream>>>(
        (const float4*)x, xh, total4x, edst, counts, rank, E,
        Wq1, Wk1, Wv1, Ws1, Wq2, Wk2, Wv2, Ws2, Wo,
        bq1, bk1, bv1, bs1, bq2, bk2, bv2, bs2,
        Wc1, Wc2, Wot, bc1, bc2);

    int nblkS = (N + 511) / 512;                  // 98 for N=50000 (<=128 req'd)
    scan_part_k<<<nblkS, 256, 0, stream>>>(counts, part, N);
    scan_top_k<<<1, 128, 0, stream>>>(part, nblkS);
    scan_fix_k<<<nblkS, 256, 0, stream>>>(counts, part, offs, N);
    scatter_k<<<(E + 255) / 256, 256, 0, stream>>>(esrc, edst, eattr, offs, rank,
                                                   edat, E);

    int nbx = (N + BM - 1) / BM;
    dim3 gqkvs(nbx * 8);                              // 1-D grid for XCD swizzle
    int nGroups = (N + 3) / 4;
    int gaBlocks = nGroups < 2048 ? nGroups : 2048;   // persistent blocks (proven R8 config)
    int total4 = N * (HD / 4);
    dim3 gl((total4 / 4 + 255) / 256);
    dim3 gout((N + 127) / 128);

    // ---- layer 1 ----
    gemm_mfma<<<gqkvs, 256, 0, stream>>>(xh, Wc1, bc1, qkvs, kv8, N, IN_DIM, 1024);
    attn_k<<<gaBlocks, 256, 0, stream>>>((const uint2*)qkvs, (const uint2*)kv8, We1,
                                         hwork, edat, offs, stats, N, nGroups);
    ln_apply<<<gl, 256, 0, stream>>>((const uint2*)hwork, hio,
                                     (const float4*)lnw1, (const float4*)lnb1,
                                     stats, (double)N * HD, total4);

    // ---- layer 2 ----
    gemm_mfma<<<gqkvs, 256, 0, stream>>>(hio, Wc2, bc2, qkvs, kv8, N, HD, 1024);
    attn_k<<<gaBlocks, 256, 0, stream>>>((const uint2*)qkvs, (const uint2*)kv8, We2,
                                         hwork, edat, offs, stats + 2, N, nGroups);
    ln_apply<<<gl, 256, 0, stream>>>((const uint2*)hwork, hio,
                                     (const float4*)lnw2, (const float4*)lnb2,
                                     stats + 2, (double)N * HD, total4);

    // ---- output projection (fp32 out, dedicated 128x64 kernel) ----
    gemm_out_k<<<gout, 256, 0, stream>>>(hio, Wot, bo, (float*)d_out, N);
}